// Round 16
// baseline (309.016 us; speedup 1.0000x reference)
//
#include <hip/hip_runtime.h>

#define FDIM  128
#define NTT   16          // trees per block
#define RS    136         // bf16 row stride for sXb/sAux
#define RSH   144         // bf16 row stride for sH (288B, 16B-aligned)
#define FCRS  400         // bf16 row stride for sFC (800B, 16B-aligned)

typedef __attribute__((ext_vector_type(8))) short bf16x8;
typedef __attribute__((ext_vector_type(4))) float f32x4;

// explicit AGPR parking (gfx950 unified RF)
#define APARKF(dst, src) asm volatile("v_accvgpr_write_b32 %0, %1" : "=a"(dst) : "v"(src))
#define AREADF(dst, src) asm volatile("v_accvgpr_read_b32 %0, %1"  : "=v"(dst) : "a"(src))

__device__ __forceinline__ unsigned short f2bf(float f){
    unsigned u = __builtin_bit_cast(unsigned, f);
    u += 0x7fffu + ((u >> 16) & 1u);          // RNE
    return (unsigned short)(u >> 16);
}
__device__ __forceinline__ float bf2f(unsigned short b){
    unsigned u = ((unsigned)b) << 16;
    return __builtin_bit_cast(float, u);
}
__device__ __forceinline__ unsigned cvtpk(float lo, float hi){
    unsigned r;
    asm("v_cvt_pk_bf16_f32 %0, %1, %2" : "=v"(r) : "v"(lo), "v"(hi));
    return r;
}
__device__ __forceinline__ float sigf(float x){ return 1.0f/(1.0f+__expf(-x)); }
__device__ __forceinline__ float tanh_(float x){ return 1.0f - 2.0f/(__expf(2.0f*x)+1.0f); }

// ---- fused fp32 -> bf16 conversion of all 5 weight matrices (1 launch) ----
__global__ void cvt_all(const float* __restrict__ W_iou, const float* __restrict__ U_iou,
                        const float* __restrict__ W_c,   const float* __restrict__ W_f,
                        const float* __restrict__ U_f,   unsigned short* __restrict__ dst)
{
    int i = blockIdx.x * 256 + threadIdx.x;      // float4 index, 0..69631
    const float* src; int base;
    if      (i < 12288){ src = W_iou; base = 0; }
    else if (i < 49152){ src = U_iou; base = 12288; }
    else if (i < 61440){ src = W_c;   base = 49152; }
    else if (i < 65536){ src = W_f;   base = 61440; }
    else               { src = U_f;   base = 65536; }
    float4 v = ((const float4*)src)[i - base];
    ushort4 b;
    b.x = f2bf(v.x); b.y = f2bf(v.y); b.z = f2bf(v.z); b.w = f2bf(v.w);
    ((ushort4*)dst)[i] = b;
}

__global__ __launch_bounds__(512, 6) void treelstm_mfma(
    const float* __restrict__ X,
    const unsigned short* __restrict__ Wiou,   // [384][128] bf16
    const unsigned short* __restrict__ Uiou,   // [384][384] bf16
    const unsigned short* __restrict__ Wc,     // [128][384] bf16
    const unsigned short* __restrict__ Wf,     // [128][128] bf16
    const unsigned short* __restrict__ Uf,     // [128][128] bf16
    const float* __restrict__ b_iou,
    const float* __restrict__ b_c,
    const float* __restrict__ b_f,
    float* __restrict__ Hout)
{
    // LDS 35584 B -> 3+ blocks/CU (register cap 84 -> 24 waves/CU target)
    // [0,12800)      sFC  [16][400] bf16  (alias; leaf-X rows dead after Pass O)
    // [0,17408)      sXb  [64][136] bf16  (leaves 0..47 = 3t+pos, parents 48+t)
    // [17408,31232)  sH   [48][144] bf16  (leaf h)
    // [31232,35584)  sAux [16][136] bf16  (FPRE, then parent h)
    __shared__ char lds[35584];
    unsigned short* sXb  = (unsigned short*)lds;
    unsigned short* sFC  = (unsigned short*)lds;
    unsigned short* sH   = (unsigned short*)(lds + 17408);
    unsigned short* sAux = (unsigned short*)(lds + 31232);

    const int tid  = threadIdx.x;
    const int w    = tid >> 6;
    const int lane = tid & 63;
    const int l15  = lane & 15;
    const int l4   = lane >> 4;
    const int jj   = w * 16 + l15;             // wave's output column (0..127 per gate)
    const size_t baseN = (size_t)blockIdx.x * (NTT*4);

    // ---- P0: load X (64 rows), permute rows, convert bf16 (2x2-load halves) ----
    {
        const f32x4* gx = (const f32x4*)(X + baseN * FDIM);
        #pragma unroll
        for (int it = 0; it < 2; ++it){
            int idx  = tid + it * 512;          // 0..1023
            int nrow = idx >> 5;                // node 0..63
            int c4   = (idx & 31) << 2;
            int t = nrow >> 2, pos = nrow & 3;
            int srow = (pos < 3) ? (t*3 + pos) : (48 + t);
            f32x4 v = gx[idx];
            uint2 pr; pr.x = cvtpk(v[0], v[1]); pr.y = cvtpk(v[2], v[3]);
            *(uint2*)&sXb[srow * RS + c4] = pr;
        }
        __builtin_amdgcn_sched_barrier(0);
        #pragma unroll
        for (int it = 2; it < 4; ++it){
            int idx  = tid + it * 512;
            int nrow = idx >> 5;
            int c4   = (idx & 31) << 2;
            int t = nrow >> 2, pos = nrow & 3;
            int srow = (pos < 3) ? (t*3 + pos) : (48 + t);
            f32x4 v = gx[idx];
            uint2 pr; pr.x = cvtpk(v[0], v[1]); pr.y = cvtpk(v[2], v[3]);
            *(uint2*)&sXb[srow * RS + c4] = pr;
        }
    }
    __builtin_amdgcn_sched_barrier(0);

    // ---- Pass-I weights (16 VGPRs); latency hides under barrier wait ----
    bf16x8 BwI[4];
    #pragma unroll
    for (int ks = 0; ks < 4; ++ks)
        BwI[ks] = *(const bf16x8*)(Wiou + (size_t)(0*FDIM + jj)*FDIM + ks*32 + l4*8);
    __syncthreads();                           // B1

    // ---- Pass I: leaf i-preacts -> packed bf16 AGPR; parent pI -> AGPR ----
    unsigned aIpk[3][2];                       // AGPR-parked leaf i-preacts (bf16 pairs)
    float pIp[4];                              // AGPR-parked parent i-preacts (f32)
    #pragma unroll
    for (int mt = 0; mt < 3; ++mt){
        f32x4 aI = {0.f,0.f,0.f,0.f};
        #pragma unroll
        for (int ks = 0; ks < 4; ++ks){
            bf16x8 A = *(const bf16x8*)&sXb[(mt*16 + l15)*RS + ks*32 + l4*8];
            aI = __builtin_amdgcn_mfma_f32_16x16x32_bf16(A, BwI[ks], aI, 0,0,0);
        }
        #pragma unroll
        for (int rp = 0; rp < 2; ++rp){
            unsigned pk = cvtpk(aI[rp*2], aI[rp*2+1]);
            APARKF(aIpk[mt][rp], pk);
        }
    }
    {
        f32x4 c = {0.f,0.f,0.f,0.f};
        #pragma unroll
        for (int ks = 0; ks < 4; ++ks){
            bf16x8 A = *(const bf16x8*)&sXb[(48 + l15)*RS + ks*32 + l4*8];
            c = __builtin_amdgcn_mfma_f32_16x16x32_bf16(A, BwI[ks], c, 0,0,0);
        }
        #pragma unroll
        for (int r = 0; r < 4; ++r) APARKF(pIp[r], c[r]);
    }
    __builtin_amdgcn_sched_barrier(0);         // F1

    // ---- Pass U: cv = sig(i)*tanh(u) -> packed bf16 AGPR; parent pU -> AGPR ----
    bf16x8 BwU[4];
    #pragma unroll
    for (int ks = 0; ks < 4; ++ks)
        BwU[ks] = *(const bf16x8*)(Wiou + (size_t)(2*FDIM + jj)*FDIM + ks*32 + l4*8);
    const float bi = b_iou[jj], bu = b_iou[2*FDIM + jj];
    unsigned cpk[3][2];                        // AGPR-parked cv pairs
    float pUp[4];
    #pragma unroll
    for (int mt = 0; mt < 3; ++mt){
        f32x4 aU = {0.f,0.f,0.f,0.f};
        #pragma unroll
        for (int ks = 0; ks < 4; ++ks){
            bf16x8 A = *(const bf16x8*)&sXb[(mt*16 + l15)*RS + ks*32 + l4*8];
            aU = __builtin_amdgcn_mfma_f32_16x16x32_bf16(A, BwU[ks], aU, 0,0,0);
        }
        #pragma unroll
        for (int rp = 0; rp < 2; ++rp){
            unsigned ipk; AREADF(ipk, aIpk[mt][rp]);
            float i0 = bf2f((unsigned short)(ipk & 0xffffu));
            float i1 = bf2f((unsigned short)(ipk >> 16));
            float cv0 = sigf(i0 + bi) * tanh_(aU[rp*2]   + bu);
            float cv1 = sigf(i1 + bi) * tanh_(aU[rp*2+1] + bu);
            unsigned pk = cvtpk(cv0, cv1);
            APARKF(cpk[mt][rp], pk);
        }
    }
    {
        f32x4 c = {0.f,0.f,0.f,0.f};
        #pragma unroll
        for (int ks = 0; ks < 4; ++ks){
            bf16x8 A = *(const bf16x8*)&sXb[(48 + l15)*RS + ks*32 + l4*8];
            c = __builtin_amdgcn_mfma_f32_16x16x32_bf16(A, BwU[ks], c, 0,0,0);
        }
        #pragma unroll
        for (int r = 0; r < 4; ++r) APARKF(pUp[r], c[r]);
    }
    __builtin_amdgcn_sched_barrier(0);         // F2

    // ---- Pass O: hv = sig(o)*tanh(cv) -> sH; parent pO -> AGPR ----
    bf16x8 BwO[4];
    #pragma unroll
    for (int ks = 0; ks < 4; ++ks)
        BwO[ks] = *(const bf16x8*)(Wiou + (size_t)(1*FDIM + jj)*FDIM + ks*32 + l4*8);
    const float bo = b_iou[FDIM + jj];
    float pOp[4];
    #pragma unroll
    for (int mt = 0; mt < 3; ++mt){
        f32x4 aO = {0.f,0.f,0.f,0.f};
        #pragma unroll
        for (int ks = 0; ks < 4; ++ks){
            bf16x8 A = *(const bf16x8*)&sXb[(mt*16 + l15)*RS + ks*32 + l4*8];
            aO = __builtin_amdgcn_mfma_f32_16x16x32_bf16(A, BwO[ks], aO, 0,0,0);
        }
        #pragma unroll
        for (int rp = 0; rp < 2; ++rp){
            unsigned pk; AREADF(pk, cpk[mt][rp]);
            #pragma unroll
            for (int q = 0; q < 2; ++q){
                int r = rp*2 + q;
                int li = mt*16 + l4*4 + r;     // leaf 0..47
                float cv = bf2f((unsigned short)((pk >> (16*q)) & 0xffffu));
                float hv = sigf(aO[r]+bo) * tanh_(cv);
                sH[li*RSH + jj] = f2bf(hv);
            }
        }
    }
    {
        f32x4 c = {0.f,0.f,0.f,0.f};
        #pragma unroll
        for (int ks = 0; ks < 4; ++ks){
            bf16x8 A = *(const bf16x8*)&sXb[(48 + l15)*RS + ks*32 + l4*8];
            c = __builtin_amdgcn_mfma_f32_16x16x32_bf16(A, BwO[ks], c, 0,0,0);
        }
        #pragma unroll
        for (int r = 0; r < 4; ++r) APARKF(pOp[r], c[r]);
    }
    __builtin_amdgcn_sched_barrier(0);         // F3

    // ---- Pass Wf: parent fp; FPRE -> sAux after barrier ----
    bf16x8 Bfr[4];
    #pragma unroll
    for (int ks = 0; ks < 4; ++ks)
        Bfr[ks] = *(const bf16x8*)(Wf + (size_t)jj*FDIM + ks*32 + l4*8);
    const float bfv = b_f[jj];
    f32x4 fp = {0.f,0.f,0.f,0.f};
    #pragma unroll
    for (int ks = 0; ks < 4; ++ks){
        bf16x8 A = *(const bf16x8*)&sXb[(48 + l15)*RS + ks*32 + l4*8];
        fp = __builtin_amdgcn_mfma_f32_16x16x32_bf16(A, Bfr[ks], fp, 0,0,0);
    }
    __syncthreads();                           // B1.5: all X reads done; sH visible

    #pragma unroll
    for (int r = 0; r < 4; ++r)
        sAux[(l4*4 + r)*RS + jj] = f2bf(fp[r] + bfv);

    __builtin_amdgcn_sched_barrier(0);         // F4

    // ---- P2: pIOU += Uiou @ concat(h_children); C re-inited from AGPR parks ----
    f32x4 pI, pU, pO;
    #pragma unroll
    for (int r = 0; r < 4; ++r){
        AREADF(pI[r], pIp[r]);
        AREADF(pU[r], pUp[r]);
        AREADF(pO[r], pOp[r]);
    }
    {
        bf16x8 Up[2][3];
        #pragma unroll
        for (int p = 0; p < 2; ++p)
            #pragma unroll
            for (int g = 0; g < 3; ++g)
                Up[p][g] = *(const bf16x8*)(Uiou + (size_t)(g*FDIM + jj)*384 + p*32 + l4*8);
        #pragma unroll
        for (int ks = 0; ks < 12; ++ks){
            bf16x8 A = *(const bf16x8*)&sH[(3*l15 + (ks>>2))*RSH + (ks&3)*32 + l4*8];
            bf16x8 b0 = Up[ks&1][0], b1 = Up[ks&1][1], b2 = Up[ks&1][2];
            if (ks < 10){
                #pragma unroll
                for (int g = 0; g < 3; ++g)
                    Up[ks&1][g] = *(const bf16x8*)(Uiou + (size_t)(g*FDIM + jj)*384 + (ks+2)*32 + l4*8);
            }
            pI = __builtin_amdgcn_mfma_f32_16x16x32_bf16(A, b0, pI, 0,0,0);
            pO = __builtin_amdgcn_mfma_f32_16x16x32_bf16(A, b1, pO, 0,0,0);
            pU = __builtin_amdgcn_mfma_f32_16x16x32_bf16(A, b2, pU, 0,0,0);
        }
    }

    // ---- fold parent gates; park in AGPR ----
    float giup[4], gop[4];
    #pragma unroll
    for (int r = 0; r < 4; ++r){
        float giu = sigf(pI[r]+bi) * tanh_(pU[r]+bu);
        float go  = sigf(pO[r]+bo);
        APARKF(giup[r], giu);
        APARKF(gop[r],  go);
    }
    __builtin_amdgcn_sched_barrier(0);         // F5

    // ---- P3: f = sig(FPRE + Uf@h_child); fc = f * cv -> sFC bf16 ----
    {
        bf16x8 Bu[4];
        #pragma unroll
        for (int ks = 0; ks < 4; ++ks)
            Bu[ks] = *(const bf16x8*)(Uf + (size_t)jj*FDIM + ks*32 + l4*8);
        #pragma unroll
        for (int mt = 0; mt < 3; ++mt){
            f32x4 acc = {0.f,0.f,0.f,0.f};
            #pragma unroll
            for (int ks = 0; ks < 4; ++ks){
                bf16x8 A = *(const bf16x8*)&sH[(mt*16 + l15)*RSH + ks*32 + l4*8];
                acc = __builtin_amdgcn_mfma_f32_16x16x32_bf16(A, Bu[ks], acc, 0,0,0);
            }
            #pragma unroll
            for (int rp = 0; rp < 2; ++rp){
                unsigned pk; AREADF(pk, cpk[mt][rp]);
                #pragma unroll
                for (int q = 0; q < 2; ++q){
                    int r = rp*2 + q;
                    int li = mt*16 + l4*4 + r;
                    int t = li / 3, el = li - 3*t;
                    float f  = sigf(acc[r] + bf2f(sAux[t*RS + jj]));
                    float cv = bf2f((unsigned short)((pk >> (16*q)) & 0xffffu));
                    sFC[t*FCRS + el*FDIM + jj] = f2bf(f * cv);
                }
            }
        }
    }
    __syncthreads();                           // B3: sFC complete; FPRE reads done

    // ---- P4: c_p = i*u + Wc@fc + b_c ; h_p (bf16) -> sAux ----
    {
        const float bc = b_c[jj];
        f32x4 aC = {0.f,0.f,0.f,0.f};
        #pragma unroll
        for (int ks = 0; ks < 6; ++ks){
            bf16x8 B  = *(const bf16x8*)(Wc + (size_t)jj*384 + ks*32 + l4*8);
            bf16x8 A0 = *(const bf16x8*)&sFC[l15*FCRS + ks*32 + l4*8];
            aC = __builtin_amdgcn_mfma_f32_16x16x32_bf16(A0, B, aC, 0,0,0);
        }
        __builtin_amdgcn_sched_barrier(0);     // F6: split Wc load clusters
        #pragma unroll
        for (int ks = 6; ks < 12; ++ks){
            bf16x8 B  = *(const bf16x8*)(Wc + (size_t)jj*384 + ks*32 + l4*8);
            bf16x8 A0 = *(const bf16x8*)&sFC[l15*FCRS + ks*32 + l4*8];
            aC = __builtin_amdgcn_mfma_f32_16x16x32_bf16(A0, B, aC, 0,0,0);
        }
        #pragma unroll
        for (int r = 0; r < 4; ++r){
            float giu, go;
            AREADF(giu, giup[r]);
            AREADF(go,  gop[r]);
            float cp = giu + aC[r] + bc;
            float hp = go * tanh_(cp);
            sAux[(l4*4 + r)*RS + jj] = f2bf(hp);
        }
    }
    __syncthreads();                           // B4

    // ---- final dump: bf16 -> f32, full-line coalesced stores ----
    {
        float* go_ = Hout + baseN * FDIM;
        #pragma unroll
        for (int it = 0; it < 4; ++it){
            int idx  = tid + it * 512;          // 0..2047
            int nrow = idx >> 5;                // node 0..63 (global order)
            int c4   = (idx & 31) << 2;
            int t = nrow >> 2, pos = nrow & 3;
            ushort4 hb = (pos < 3) ? *(const ushort4*)&sH[(t*3 + pos)*RSH + c4]
                                   : *(const ushort4*)&sAux[t*RS + c4];
            f32x4 v;
            v[0] = bf2f(hb.x); v[1] = bf2f(hb.y); v[2] = bf2f(hb.z); v[3] = bf2f(hb.w);
            *(f32x4*)(go_ + nrow*FDIM + c4) = v;
        }
    }
}

extern "C" void kernel_launch(void* const* d_in, const int* in_sizes, int n_in,
                              void* d_out, int out_size, void* d_ws, size_t ws_size,
                              hipStream_t stream)
{
    const float* forest = (const float*)d_in[0];
    const float* W_iou  = (const float*)d_in[4];
    const float* b_iou  = (const float*)d_in[5];
    const float* U_iou  = (const float*)d_in[6];
    const float* W_c    = (const float*)d_in[7];
    const float* b_c    = (const float*)d_in[8];
    const float* W_f    = (const float*)d_in[9];
    const float* b_f    = (const float*)d_in[10];
    const float* U_f    = (const float*)d_in[11];
    float* Hout = (float*)d_out;

    unsigned short* wsb = (unsigned short*)d_ws;
    unsigned short* bWiou = wsb;                // 49152 elems
    unsigned short* bUiou = wsb + 49152;        // 147456
    unsigned short* bWc   = wsb + 196608;       // 49152
    unsigned short* bWf   = wsb + 245760;       // 16384
    unsigned short* bUf   = wsb + 262144;       // 16384

    hipLaunchKernelGGL(cvt_all, dim3(272), dim3(256), 0, stream,
                       W_iou, U_iou, W_c, W_f, U_f, wsb);

    const int trees = in_sizes[0] / (4 * FDIM); // 65536
    const int grid  = trees / NTT;              // 4096

    hipLaunchKernelGGL(treelstm_mfma, dim3(grid), dim3(512), 0, stream,
                       forest, bWiou, bUiou, bWc, bWf, bUf, b_iou, b_c, b_f, Hout);
}

// Round 17
// 205.295 us; speedup vs baseline: 1.5052x; 1.5052x over previous
//
#include <hip/hip_runtime.h>

#define FDIM  128
#define NTT   32          // trees per block
#define RS    136         // bf16 row stride for sXb/sAux
#define RSH   144         // bf16 row stride for sH  (288B = 16B-aligned; 72dw %32=8)
#define FCRS  400         // bf16 row stride for sFC (800B = 16B-aligned; 200dw %32=8)

typedef __attribute__((ext_vector_type(8))) short bf16x8;
typedef __attribute__((ext_vector_type(4))) float f32x4;

// explicit AGPR parking (gfx950 unified RF)
#define APARKF(dst, src) asm volatile("v_accvgpr_write_b32 %0, %1" : "=a"(dst) : "v"(src))
#define AREADF(dst, src) asm volatile("v_accvgpr_read_b32 %0, %1"  : "=v"(dst) : "a"(src))

__device__ __forceinline__ unsigned short f2bf(float f){
    unsigned u = __builtin_bit_cast(unsigned, f);
    u += 0x7fffu + ((u >> 16) & 1u);          // RNE
    return (unsigned short)(u >> 16);
}
__device__ __forceinline__ float bf2f(unsigned short b){
    unsigned u = ((unsigned)b) << 16;
    return __builtin_bit_cast(float, u);
}
__device__ __forceinline__ unsigned cvtpk(float lo, float hi){
    unsigned r;
    asm("v_cvt_pk_bf16_f32 %0, %1, %2" : "=v"(r) : "v"(lo), "v"(hi));
    return r;
}
__device__ __forceinline__ float sigf(float x){ return 1.0f/(1.0f+__expf(-x)); }
__device__ __forceinline__ float tanh_(float x){ return 1.0f - 2.0f/(__expf(2.0f*x)+1.0f); }

// ---- fused fp32 -> bf16 conversion of all 5 weight matrices (1 launch) ----
__global__ void cvt_all(const float* __restrict__ W_iou, const float* __restrict__ U_iou,
                        const float* __restrict__ W_c,   const float* __restrict__ W_f,
                        const float* __restrict__ U_f,   unsigned short* __restrict__ dst)
{
    int i = blockIdx.x * 256 + threadIdx.x;      // float4 index, 0..69631
    const float* src; int base;
    if      (i < 12288){ src = W_iou; base = 0; }
    else if (i < 49152){ src = U_iou; base = 12288; }
    else if (i < 61440){ src = W_c;   base = 49152; }
    else if (i < 65536){ src = W_f;   base = 61440; }
    else               { src = U_f;   base = 65536; }
    float4 v = ((const float4*)src)[i - base];
    ushort4 b;
    b.x = f2bf(v.x); b.y = f2bf(v.y); b.z = f2bf(v.z); b.w = f2bf(v.w);
    ((ushort4*)dst)[i] = b;
}

__global__ __launch_bounds__(512, 4) void treelstm_mfma(
    const float* __restrict__ X,
    const unsigned short* __restrict__ Wiou,   // [384][128] bf16
    const unsigned short* __restrict__ Uiou,   // [384][384] bf16
    const unsigned short* __restrict__ Wc,     // [128][384] bf16
    const unsigned short* __restrict__ Wf,     // [128][128] bf16
    const unsigned short* __restrict__ Uf,     // [128][128] bf16
    const float* __restrict__ b_iou,
    const float* __restrict__ b_c,
    const float* __restrict__ b_f,
    float* __restrict__ Hout)
{
    // LDS 62464 B -> 2 blocks/CU
    // [0,25600)      sFC  [32][400] bf16   (alias; leaf-X dead after Pass O)
    // [0,34816)      sXb  [128][136] bf16  (leaves 0..95 = 3t+pos, parents 96+t)
    // [26112,34816)  sAux [32][136] bf16   (FPRE, then parent h)
    // [34816,62464)  sH   [96][144] bf16   (leaf h)
    __shared__ char lds[62464];
    unsigned short* sXb  = (unsigned short*)lds;
    unsigned short* sFC  = (unsigned short*)lds;
    unsigned short* sAux = (unsigned short*)(lds + 26112);
    unsigned short* sH   = (unsigned short*)(lds + 34816);

    const int tid  = threadIdx.x;
    const int w    = tid >> 6;
    const int lane = tid & 63;
    const int l15  = lane & 15;
    const int l4   = lane >> 4;
    const int jj   = w * 16 + l15;             // wave's output column (0..127 per gate)
    const size_t baseN = (size_t)blockIdx.x * (NTT*4);

    // ---- P0: load X (128 rows), permute rows, convert bf16 (2x4-load halves) ----
    {
        const f32x4* gx = (const f32x4*)(X + baseN * FDIM);
        #pragma unroll
        for (int it = 0; it < 4; ++it){
            int idx  = tid + it * 512;
            int nrow = idx >> 5;
            int c4   = (idx & 31) << 2;
            int t = nrow >> 2, pos = nrow & 3;
            int srow = (pos < 3) ? (t*3 + pos) : (96 + t);
            f32x4 v = gx[idx];
            uint2 pr; pr.x = cvtpk(v[0], v[1]); pr.y = cvtpk(v[2], v[3]);
            *(uint2*)&sXb[srow * RS + c4] = pr;
        }
        __builtin_amdgcn_sched_barrier(0);     // bound in-flight loads to 4/thread
        #pragma unroll
        for (int it = 4; it < 8; ++it){
            int idx  = tid + it * 512;
            int nrow = idx >> 5;
            int c4   = (idx & 31) << 2;
            int t = nrow >> 2, pos = nrow & 3;
            int srow = (pos < 3) ? (t*3 + pos) : (96 + t);
            f32x4 v = gx[idx];
            uint2 pr; pr.x = cvtpk(v[0], v[1]); pr.y = cvtpk(v[2], v[3]);
            *(uint2*)&sXb[srow * RS + c4] = pr;
        }
    }
    __builtin_amdgcn_sched_barrier(0);

    // ---- Pass-I weights (16 VGPRs); latency hides under barrier wait ----
    bf16x8 BwI[4];
    #pragma unroll
    for (int ks = 0; ks < 4; ++ks)
        BwI[ks] = *(const bf16x8*)(Wiou + (size_t)(0*FDIM + jj)*FDIM + ks*32 + l4*8);
    __syncthreads();                           // B1

    // ---- Pass I: leaf i-preacts -> AGPR; parent pI -> AGPR ----
    float aIp[6][4];                           // AGPR-parked leaf i-preacts
    float pIp[2][4];                           // AGPR-parked parent i-preacts
    #pragma unroll
    for (int mt = 0; mt < 6; ++mt){
        f32x4 aI = {0.f,0.f,0.f,0.f};
        #pragma unroll
        for (int ks = 0; ks < 4; ++ks){
            bf16x8 A = *(const bf16x8*)&sXb[(mt*16 + l15)*RS + ks*32 + l4*8];
            aI = __builtin_amdgcn_mfma_f32_16x16x32_bf16(A, BwI[ks], aI, 0,0,0);
        }
        #pragma unroll
        for (int r = 0; r < 4; ++r) APARKF(aIp[mt][r], aI[r]);
    }
    #pragma unroll
    for (int pt = 0; pt < 2; ++pt){
        f32x4 c = {0.f,0.f,0.f,0.f};
        #pragma unroll
        for (int ks = 0; ks < 4; ++ks){
            bf16x8 A = *(const bf16x8*)&sXb[(96 + pt*16 + l15)*RS + ks*32 + l4*8];
            c = __builtin_amdgcn_mfma_f32_16x16x32_bf16(A, BwI[ks], c, 0,0,0);
        }
        #pragma unroll
        for (int r = 0; r < 4; ++r) APARKF(pIp[pt][r], c[r]);
    }
    __builtin_amdgcn_sched_barrier(0);         // F1

    // ---- Pass U: cv = sig(i)*tanh(u) -> packed bf16 AGPR; parent pU -> AGPR ----
    bf16x8 BwU[4];
    #pragma unroll
    for (int ks = 0; ks < 4; ++ks)
        BwU[ks] = *(const bf16x8*)(Wiou + (size_t)(2*FDIM + jj)*FDIM + ks*32 + l4*8);
    const float bi = b_iou[jj], bu = b_iou[2*FDIM + jj];
    unsigned cpk[6][2];                        // AGPR-parked cv pairs
    float pUp[2][4];
    #pragma unroll
    for (int mt = 0; mt < 6; ++mt){
        f32x4 aU = {0.f,0.f,0.f,0.f};
        #pragma unroll
        for (int ks = 0; ks < 4; ++ks){
            bf16x8 A = *(const bf16x8*)&sXb[(mt*16 + l15)*RS + ks*32 + l4*8];
            aU = __builtin_amdgcn_mfma_f32_16x16x32_bf16(A, BwU[ks], aU, 0,0,0);
        }
        #pragma unroll
        for (int rp = 0; rp < 2; ++rp){
            float i0, i1;
            AREADF(i0, aIp[mt][rp*2]);
            AREADF(i1, aIp[mt][rp*2+1]);
            float cv0 = sigf(i0 + bi) * tanh_(aU[rp*2]   + bu);
            float cv1 = sigf(i1 + bi) * tanh_(aU[rp*2+1] + bu);
            unsigned pk = cvtpk(cv0, cv1);     // lo16 = cv0 (q=0), hi16 = cv1
            APARKF(cpk[mt][rp], pk);
        }
    }
    #pragma unroll
    for (int pt = 0; pt < 2; ++pt){
        f32x4 c = {0.f,0.f,0.f,0.f};
        #pragma unroll
        for (int ks = 0; ks < 4; ++ks){
            bf16x8 A = *(const bf16x8*)&sXb[(96 + pt*16 + l15)*RS + ks*32 + l4*8];
            c = __builtin_amdgcn_mfma_f32_16x16x32_bf16(A, BwU[ks], c, 0,0,0);
        }
        #pragma unroll
        for (int r = 0; r < 4; ++r) APARKF(pUp[pt][r], c[r]);
    }
    __builtin_amdgcn_sched_barrier(0);         // F2

    // ---- Pass O: hv = sig(o)*tanh(cv) -> sH; parent pO -> AGPR ----
    bf16x8 BwO[4];
    #pragma unroll
    for (int ks = 0; ks < 4; ++ks)
        BwO[ks] = *(const bf16x8*)(Wiou + (size_t)(1*FDIM + jj)*FDIM + ks*32 + l4*8);
    const float bo = b_iou[FDIM + jj];
    float pOp[2][4];
    #pragma unroll
    for (int mt = 0; mt < 6; ++mt){
        f32x4 aO = {0.f,0.f,0.f,0.f};
        #pragma unroll
        for (int ks = 0; ks < 4; ++ks){
            bf16x8 A = *(const bf16x8*)&sXb[(mt*16 + l15)*RS + ks*32 + l4*8];
            aO = __builtin_amdgcn_mfma_f32_16x16x32_bf16(A, BwO[ks], aO, 0,0,0);
        }
        #pragma unroll
        for (int rp = 0; rp < 2; ++rp){
            unsigned pk; AREADF(pk, cpk[mt][rp]);
            #pragma unroll
            for (int q = 0; q < 2; ++q){
                int r = rp*2 + q;
                int li = mt*16 + l4*4 + r;     // leaf 0..95
                float cv = bf2f((unsigned short)((pk >> (16*q)) & 0xffffu));
                float hv = sigf(aO[r]+bo) * tanh_(cv);
                sH[li*RSH + jj] = f2bf(hv);
            }
        }
    }
    #pragma unroll
    for (int pt = 0; pt < 2; ++pt){
        f32x4 c = {0.f,0.f,0.f,0.f};
        #pragma unroll
        for (int ks = 0; ks < 4; ++ks){
            bf16x8 A = *(const bf16x8*)&sXb[(96 + pt*16 + l15)*RS + ks*32 + l4*8];
            c = __builtin_amdgcn_mfma_f32_16x16x32_bf16(A, BwO[ks], c, 0,0,0);
        }
        #pragma unroll
        for (int r = 0; r < 4; ++r) APARKF(pOp[pt][r], c[r]);
    }
    __builtin_amdgcn_sched_barrier(0);         // F3

    // ---- Pass Wf: parent fp; FPRE -> sAux after barrier ----
    bf16x8 Bfr[4];
    #pragma unroll
    for (int ks = 0; ks < 4; ++ks)
        Bfr[ks] = *(const bf16x8*)(Wf + (size_t)jj*FDIM + ks*32 + l4*8);
    const float bfv = b_f[jj];
    f32x4 fp[2];
    #pragma unroll
    for (int pt = 0; pt < 2; ++pt){
        fp[pt] = (f32x4){0.f,0.f,0.f,0.f};
        #pragma unroll
        for (int ks = 0; ks < 4; ++ks){
            bf16x8 A = *(const bf16x8*)&sXb[(96 + pt*16 + l15)*RS + ks*32 + l4*8];
            fp[pt] = __builtin_amdgcn_mfma_f32_16x16x32_bf16(A, Bfr[ks], fp[pt], 0,0,0);
        }
    }
    __syncthreads();                           // B1.5: all X reads done; sH visible

    #pragma unroll
    for (int pt = 0; pt < 2; ++pt)
        #pragma unroll
        for (int r = 0; r < 4; ++r)
            sAux[(pt*16 + l4*4 + r)*RS + jj] = f2bf(fp[pt][r] + bfv);

    // ---- EARLY leaf-h dump: 96 rows x 512B full lines; overlaps P2/P3/P4 ----
    {
        float* go_ = Hout + baseN * FDIM;
        #pragma unroll
        for (int it = 0; it < 6; ++it){
            int idx  = tid + it * 512;          // 0..3071 float4s
            int li   = idx >> 5;                // leaf 0..95
            int c4   = (idx & 31) << 2;
            int t = li / 3, pos = li - 3*t;
            ushort4 hb = *(const ushort4*)&sH[li*RSH + c4];
            f32x4 v;
            v[0] = bf2f(hb.x); v[1] = bf2f(hb.y); v[2] = bf2f(hb.z); v[3] = bf2f(hb.w);
            *(f32x4*)(go_ + (t*4 + pos)*FDIM + c4) = v;
        }
    }

    __builtin_amdgcn_sched_barrier(0);         // F4

    // ---- P2: pIOU += Uiou @ concat(h_children); C re-inited from AGPR parks ----
    f32x4 pI[2], pU[2], pO[2];
    #pragma unroll
    for (int pt = 0; pt < 2; ++pt)
        #pragma unroll
        for (int r = 0; r < 4; ++r){
            AREADF(pI[pt][r], pIp[pt][r]);
            AREADF(pU[pt][r], pUp[pt][r]);
            AREADF(pO[pt][r], pOp[pt][r]);
        }
    {
        bf16x8 Up[2][3];
        #pragma unroll
        for (int p = 0; p < 2; ++p)
            #pragma unroll
            for (int g = 0; g < 3; ++g)
                Up[p][g] = *(const bf16x8*)(Uiou + (size_t)(g*FDIM + jj)*384 + p*32 + l4*8);
        #pragma unroll
        for (int ks = 0; ks < 12; ++ks){
            bf16x8 A0 = *(const bf16x8*)&sH[(3*l15        + (ks>>2))*RSH + (ks&3)*32 + l4*8];
            bf16x8 A1 = *(const bf16x8*)&sH[(3*(16 + l15) + (ks>>2))*RSH + (ks&3)*32 + l4*8];
            bf16x8 b0 = Up[ks&1][0], b1 = Up[ks&1][1], b2 = Up[ks&1][2];
            if (ks < 10){
                #pragma unroll
                for (int g = 0; g < 3; ++g)
                    Up[ks&1][g] = *(const bf16x8*)(Uiou + (size_t)(g*FDIM + jj)*384 + (ks+2)*32 + l4*8);
            }
            pI[0] = __builtin_amdgcn_mfma_f32_16x16x32_bf16(A0, b0, pI[0], 0,0,0);
            pI[1] = __builtin_amdgcn_mfma_f32_16x16x32_bf16(A1, b0, pI[1], 0,0,0);
            pO[0] = __builtin_amdgcn_mfma_f32_16x16x32_bf16(A0, b1, pO[0], 0,0,0);
            pO[1] = __builtin_amdgcn_mfma_f32_16x16x32_bf16(A1, b1, pO[1], 0,0,0);
            pU[0] = __builtin_amdgcn_mfma_f32_16x16x32_bf16(A0, b2, pU[0], 0,0,0);
            pU[1] = __builtin_amdgcn_mfma_f32_16x16x32_bf16(A1, b2, pU[1], 0,0,0);
        }
    }

    // ---- fold parent gates; park in AGPR ----
    float giup[2][4], gop[2][4];
    #pragma unroll
    for (int pt = 0; pt < 2; ++pt)
        #pragma unroll
        for (int r = 0; r < 4; ++r){
            float giu = sigf(pI[pt][r]+bi) * tanh_(pU[pt][r]+bu);
            float go  = sigf(pO[pt][r]+bo);
            APARKF(giup[pt][r], giu);
            APARKF(gop[pt][r],  go);
        }
    __builtin_amdgcn_sched_barrier(0);         // F5

    // ---- P3: f = sig(FPRE + Uf@h_child); fc = f * cv -> sFC bf16 ----
    {
        bf16x8 Bu[4];
        #pragma unroll
        for (int ks = 0; ks < 4; ++ks)
            Bu[ks] = *(const bf16x8*)(Uf + (size_t)jj*FDIM + ks*32 + l4*8);
        #pragma unroll
        for (int mt = 0; mt < 6; ++mt){
            f32x4 acc = {0.f,0.f,0.f,0.f};
            #pragma unroll
            for (int ks = 0; ks < 4; ++ks){
                bf16x8 A = *(const bf16x8*)&sH[(mt*16 + l15)*RSH + ks*32 + l4*8];
                acc = __builtin_amdgcn_mfma_f32_16x16x32_bf16(A, Bu[ks], acc, 0,0,0);
            }
            #pragma unroll
            for (int rp = 0; rp < 2; ++rp){
                unsigned pk; AREADF(pk, cpk[mt][rp]);
                #pragma unroll
                for (int q = 0; q < 2; ++q){
                    int r = rp*2 + q;
                    int li = mt*16 + l4*4 + r;
                    int t = li / 3, el = li - 3*t;
                    float f  = sigf(acc[r] + bf2f(sAux[t*RS + jj]));
                    float cv = bf2f((unsigned short)((pk >> (16*q)) & 0xffffu));
                    sFC[t*FCRS + el*FDIM + jj] = f2bf(f * cv);
                }
            }
        }
    }
    __syncthreads();                           // B3: sFC complete

    // ---- P4: c_p = i*u + Wc@fc + b_c ; h_p (bf16) -> sAux ----
    {
        const float bc = b_c[jj];
        f32x4 aC0 = {0.f,0.f,0.f,0.f}, aC1 = {0.f,0.f,0.f,0.f};
        #pragma unroll
        for (int ks = 0; ks < 6; ++ks){
            bf16x8 B  = *(const bf16x8*)(Wc + (size_t)jj*384 + ks*32 + l4*8);
            bf16x8 A0 = *(const bf16x8*)&sFC[(l15     )*FCRS + ks*32 + l4*8];
            bf16x8 A1 = *(const bf16x8*)&sFC[(16 + l15)*FCRS + ks*32 + l4*8];
            aC0 = __builtin_amdgcn_mfma_f32_16x16x32_bf16(A0, B, aC0, 0,0,0);
            aC1 = __builtin_amdgcn_mfma_f32_16x16x32_bf16(A1, B, aC1, 0,0,0);
        }
        __builtin_amdgcn_sched_barrier(0);     // F6: split Wc load clusters
        #pragma unroll
        for (int ks = 6; ks < 12; ++ks){
            bf16x8 B  = *(const bf16x8*)(Wc + (size_t)jj*384 + ks*32 + l4*8);
            bf16x8 A0 = *(const bf16x8*)&sFC[(l15     )*FCRS + ks*32 + l4*8];
            bf16x8 A1 = *(const bf16x8*)&sFC[(16 + l15)*FCRS + ks*32 + l4*8];
            aC0 = __builtin_amdgcn_mfma_f32_16x16x32_bf16(A0, B, aC0, 0,0,0);
            aC1 = __builtin_amdgcn_mfma_f32_16x16x32_bf16(A1, B, aC1, 0,0,0);
        }
        #pragma unroll
        for (int pt = 0; pt < 2; ++pt){
            #pragma unroll
            for (int r = 0; r < 4; ++r){
                float giu, go;
                AREADF(giu, giup[pt][r]);
                AREADF(go,  gop[pt][r]);
                float aC = (pt ? aC1 : aC0)[r];
                float cp = giu + aC + bc;
                float hp = go * tanh_(cp);
                sAux[(pt*16 + l4*4 + r)*RS + jj] = f2bf(hp);
            }
        }
    }
    __syncthreads();                           // B4: parent h complete

    // ---- tail dump: 32 parent rows only ----
    {
        float* go_ = Hout + baseN * FDIM;
        #pragma unroll
        for (int it = 0; it < 2; ++it){
            int idx = tid + it * 512;           // 0..1023 float4s
            int t   = idx >> 5;                 // tree 0..31
            int c4  = (idx & 31) << 2;
            ushort4 hb = *(const ushort4*)&sAux[t*RS + c4];
            f32x4 v;
            v[0] = bf2f(hb.x); v[1] = bf2f(hb.y); v[2] = bf2f(hb.z); v[3] = bf2f(hb.w);
            *(f32x4*)(go_ + (t*4 + 3)*FDIM + c4) = v;
        }
    }
}

extern "C" void kernel_launch(void* const* d_in, const int* in_sizes, int n_in,
                              void* d_out, int out_size, void* d_ws, size_t ws_size,
                              hipStream_t stream)
{
    const float* forest = (const float*)d_in[0];
    const float* W_iou  = (const float*)d_in[4];
    const float* b_iou  = (const float*)d_in[5];
    const float* U_iou  = (const float*)d_in[6];
    const float* W_c    = (const float*)d_in[7];
    const float* b_c    = (const float*)d_in[8];
    const float* W_f    = (const float*)d_in[9];
    const float* b_f    = (const float*)d_in[10];
    const float* U_f    = (const float*)d_in[11];
    float* Hout = (float*)d_out;

    unsigned short* wsb = (unsigned short*)d_ws;
    unsigned short* bWiou = wsb;                // 49152 elems
    unsigned short* bUiou = wsb + 49152;        // 147456
    unsigned short* bWc   = wsb + 196608;       // 49152
    unsigned short* bWf   = wsb + 245760;       // 16384
    unsigned short* bUf   = wsb + 262144;       // 16384

    hipLaunchKernelGGL(cvt_all, dim3(272), dim3(256), 0, stream,
                       W_iou, U_iou, W_c, W_f, U_f, wsb);

    const int trees = in_sizes[0] / (4 * FDIM); // 65536
    const int grid  = trees / NTT;              // 2048

    hipLaunchKernelGGL(treelstm_mfma, dim3(grid), dim3(512), 0, stream,
                       forest, bWiou, bUiou, bWc, bWf, bUf, b_iou, b_c, b_f, Hout);
}

// Round 18
// 203.595 us; speedup vs baseline: 1.5178x; 1.0083x over previous
//
#include <hip/hip_runtime.h>

#define FDIM  128
#define NTT   32          // trees per block
#define RS    136         // bf16 row stride for sXb/sAux
#define RSH   144         // bf16 row stride for sH  (288B, 16B-aligned)
#define FCRS  400         // bf16 row stride for sFC (800B, 16B-aligned)

typedef __attribute__((ext_vector_type(8))) short bf16x8;
typedef __attribute__((ext_vector_type(4))) float f32x4;

// explicit AGPR parking (gfx950 unified RF)
#define APARKF(dst, src) asm volatile("v_accvgpr_write_b32 %0, %1" : "=a"(dst) : "v"(src))
#define AREADF(dst, src) asm volatile("v_accvgpr_read_b32 %0, %1"  : "=v"(dst) : "a"(src))

__device__ __forceinline__ unsigned short f2bf(float f){
    unsigned u = __builtin_bit_cast(unsigned, f);
    u += 0x7fffu + ((u >> 16) & 1u);          // RNE
    return (unsigned short)(u >> 16);
}
__device__ __forceinline__ float bf2f(unsigned short b){
    unsigned u = ((unsigned)b) << 16;
    return __builtin_bit_cast(float, u);
}
__device__ __forceinline__ unsigned cvtpk(float lo, float hi){
    unsigned r;
    asm("v_cvt_pk_bf16_f32 %0, %1, %2" : "=v"(r) : "v"(lo), "v"(hi));
    return r;
}
__device__ __forceinline__ float sigf(float x){ return 1.0f/(1.0f+__expf(-x)); }
__device__ __forceinline__ float tanh_(float x){ return 1.0f - 2.0f/(__expf(2.0f*x)+1.0f); }

// ---- fused fp32 -> bf16 conversion of all 5 weight matrices (1 launch) ----
__global__ void cvt_all(const float* __restrict__ W_iou, const float* __restrict__ U_iou,
                        const float* __restrict__ W_c,   const float* __restrict__ W_f,
                        const float* __restrict__ U_f,   unsigned short* __restrict__ dst)
{
    int i = blockIdx.x * 256 + threadIdx.x;      // float4 index, 0..69631
    const float* src; int base;
    if      (i < 12288){ src = W_iou; base = 0; }
    else if (i < 49152){ src = U_iou; base = 12288; }
    else if (i < 61440){ src = W_c;   base = 49152; }
    else if (i < 65536){ src = W_f;   base = 61440; }
    else               { src = U_f;   base = 65536; }
    float4 v = ((const float4*)src)[i - base];
    ushort4 b;
    b.x = f2bf(v.x); b.y = f2bf(v.y); b.z = f2bf(v.z); b.w = f2bf(v.w);
    ((ushort4*)dst)[i] = b;
}

__global__ __launch_bounds__(512, 4) void treelstm_mfma(
    const float* __restrict__ X,
    const unsigned short* __restrict__ Wiou,   // [384][128] bf16
    const unsigned short* __restrict__ Uiou,   // [384][384] bf16
    const unsigned short* __restrict__ Wc,     // [128][384] bf16
    const unsigned short* __restrict__ Wf,     // [128][128] bf16
    const unsigned short* __restrict__ Uf,     // [128][128] bf16
    const float* __restrict__ b_iou,
    const float* __restrict__ b_c,
    const float* __restrict__ b_f,
    float* __restrict__ Hout)
{
    // LDS 62464 B -> 2 blocks/CU
    // [0,25600)      sFC  [32][400] bf16   (alias; leaf-X dead after Pass B)
    // [0,34816)      sXb  [128][136] bf16  (leaves 0..95 = 3t+pos, parents 96+t)
    // [26112,34816)  sAux [32][136] bf16   (FPRE, then parent h)
    // [34816,62464)  sH   [96][144] bf16   (leaf h)
    __shared__ char lds[62464];
    unsigned short* sXb  = (unsigned short*)lds;
    unsigned short* sFC  = (unsigned short*)lds;
    unsigned short* sAux = (unsigned short*)(lds + 26112);
    unsigned short* sH   = (unsigned short*)(lds + 34816);

    const int tid  = threadIdx.x;
    const int w    = tid >> 6;
    const int lane = tid & 63;
    const int l15  = lane & 15;
    const int l4   = lane >> 4;
    const int jj   = w * 16 + l15;             // wave's output column (0..127 per gate)
    const size_t baseN = (size_t)blockIdx.x * (NTT*4);

    // ---- P0: load X (128 rows), permute rows, convert bf16 (2x4-load halves) ----
    {
        const f32x4* gx = (const f32x4*)(X + baseN * FDIM);
        #pragma unroll
        for (int it = 0; it < 4; ++it){
            int idx  = tid + it * 512;
            int nrow = idx >> 5;
            int c4   = (idx & 31) << 2;
            int t = nrow >> 2, pos = nrow & 3;
            int srow = (pos < 3) ? (t*3 + pos) : (96 + t);
            f32x4 v = gx[idx];
            uint2 pr; pr.x = cvtpk(v[0], v[1]); pr.y = cvtpk(v[2], v[3]);
            *(uint2*)&sXb[srow * RS + c4] = pr;
        }
        __builtin_amdgcn_sched_barrier(0);     // bound in-flight loads to 4/thread
        #pragma unroll
        for (int it = 4; it < 8; ++it){
            int idx  = tid + it * 512;
            int nrow = idx >> 5;
            int c4   = (idx & 31) << 2;
            int t = nrow >> 2, pos = nrow & 3;
            int srow = (pos < 3) ? (t*3 + pos) : (96 + t);
            f32x4 v = gx[idx];
            uint2 pr; pr.x = cvtpk(v[0], v[1]); pr.y = cvtpk(v[2], v[3]);
            *(uint2*)&sXb[srow * RS + c4] = pr;
        }
    }
    __builtin_amdgcn_sched_barrier(0);

    // ---- Pass-A weights: gates I and U (32 VGPRs); latency hides under barrier ----
    bf16x8 BwI[4], BwU[4];
    #pragma unroll
    for (int ks = 0; ks < 4; ++ks){
        BwI[ks] = *(const bf16x8*)(Wiou + (size_t)(0*FDIM + jj)*FDIM + ks*32 + l4*8);
        BwU[ks] = *(const bf16x8*)(Wiou + (size_t)(2*FDIM + jj)*FDIM + ks*32 + l4*8);
    }
    const float bi = b_iou[jj], bu = b_iou[2*FDIM + jj];
    __syncthreads();                           // B1

    // ---- Pass A: leaf cv = sig(i)*tanh(u) -> packed bf16 AGPR; parents -> pIp,pUp ----
    unsigned cpk[6][2];                        // AGPR-parked cv pairs
    float pIp[2][4], pUp[2][4];                // AGPR-parked parent preacts
    #pragma unroll
    for (int mt = 0; mt < 6; ++mt){
        f32x4 aI = {0.f,0.f,0.f,0.f}, aU = {0.f,0.f,0.f,0.f};
        #pragma unroll
        for (int ks = 0; ks < 4; ++ks){
            bf16x8 A = *(const bf16x8*)&sXb[(mt*16 + l15)*RS + ks*32 + l4*8];
            aI = __builtin_amdgcn_mfma_f32_16x16x32_bf16(A, BwI[ks], aI, 0,0,0);
            aU = __builtin_amdgcn_mfma_f32_16x16x32_bf16(A, BwU[ks], aU, 0,0,0);
        }
        #pragma unroll
        for (int rp = 0; rp < 2; ++rp){
            float cv0 = sigf(aI[rp*2]   + bi) * tanh_(aU[rp*2]   + bu);
            float cv1 = sigf(aI[rp*2+1] + bi) * tanh_(aU[rp*2+1] + bu);
            unsigned pk = cvtpk(cv0, cv1);     // lo16 = cv0, hi16 = cv1
            APARKF(cpk[mt][rp], pk);
        }
    }
    #pragma unroll
    for (int pt = 0; pt < 2; ++pt){
        f32x4 cI = {0.f,0.f,0.f,0.f}, cU = {0.f,0.f,0.f,0.f};
        #pragma unroll
        for (int ks = 0; ks < 4; ++ks){
            bf16x8 A = *(const bf16x8*)&sXb[(96 + pt*16 + l15)*RS + ks*32 + l4*8];
            cI = __builtin_amdgcn_mfma_f32_16x16x32_bf16(A, BwI[ks], cI, 0,0,0);
            cU = __builtin_amdgcn_mfma_f32_16x16x32_bf16(A, BwU[ks], cU, 0,0,0);
        }
        #pragma unroll
        for (int r = 0; r < 4; ++r){ APARKF(pIp[pt][r], cI[r]); APARKF(pUp[pt][r], cU[r]); }
    }
    __builtin_amdgcn_sched_barrier(0);         // F1

    // ---- Pass-B weights: gate O + Wf (reuse freed regs) ----
    bf16x8 BwO[4], Bfr[4];
    #pragma unroll
    for (int ks = 0; ks < 4; ++ks){
        BwO[ks] = *(const bf16x8*)(Wiou + (size_t)(1*FDIM + jj)*FDIM + ks*32 + l4*8);
        Bfr[ks] = *(const bf16x8*)(Wf   + (size_t)jj*FDIM + ks*32 + l4*8);
    }
    const float bo = b_iou[FDIM + jj];

    // ---- Pass B: leaf hv -> sH; parents -> pOp (park), fp (keep in regs) ----
    float pOp[2][4];
    #pragma unroll
    for (int mt = 0; mt < 6; ++mt){
        f32x4 aO = {0.f,0.f,0.f,0.f};
        #pragma unroll
        for (int ks = 0; ks < 4; ++ks){
            bf16x8 A = *(const bf16x8*)&sXb[(mt*16 + l15)*RS + ks*32 + l4*8];
            aO = __builtin_amdgcn_mfma_f32_16x16x32_bf16(A, BwO[ks], aO, 0,0,0);
        }
        #pragma unroll
        for (int rp = 0; rp < 2; ++rp){
            unsigned pk; AREADF(pk, cpk[mt][rp]);
            #pragma unroll
            for (int q = 0; q < 2; ++q){
                int r = rp*2 + q;
                int li = mt*16 + l4*4 + r;     // leaf 0..95
                float cv = bf2f((unsigned short)((pk >> (16*q)) & 0xffffu));
                float hv = sigf(aO[r]+bo) * tanh_(cv);
                sH[li*RSH + jj] = f2bf(hv);
            }
        }
    }
    f32x4 fp[2];
    #pragma unroll
    for (int pt = 0; pt < 2; ++pt){
        f32x4 cO = {0.f,0.f,0.f,0.f};
        fp[pt] = (f32x4){0.f,0.f,0.f,0.f};
        #pragma unroll
        for (int ks = 0; ks < 4; ++ks){
            bf16x8 A = *(const bf16x8*)&sXb[(96 + pt*16 + l15)*RS + ks*32 + l4*8];
            cO     = __builtin_amdgcn_mfma_f32_16x16x32_bf16(A, BwO[ks], cO, 0,0,0);
            fp[pt] = __builtin_amdgcn_mfma_f32_16x16x32_bf16(A, Bfr[ks], fp[pt], 0,0,0);
        }
        #pragma unroll
        for (int r = 0; r < 4; ++r) APARKF(pOp[pt][r], cO[r]);
    }
    __syncthreads();                           // B1.5: all X reads done; sH visible

    // ---- FPRE (bf16) -> sAux (overwrites dead parent-X rows) ----
    const float bfv = b_f[jj];
    #pragma unroll
    for (int pt = 0; pt < 2; ++pt)
        #pragma unroll
        for (int r = 0; r < 4; ++r)
            sAux[(pt*16 + l4*4 + r)*RS + jj] = f2bf(fp[pt][r] + bfv);

    // ---- EARLY leaf-h dump: 96 rows x 512B full lines; overlaps P2/P3/P4 ----
    {
        float* go_ = Hout + baseN * FDIM;
        #pragma unroll
        for (int it = 0; it < 6; ++it){
            int idx  = tid + it * 512;          // 0..3071 float4s
            int li   = idx >> 5;                // leaf 0..95
            int c4   = (idx & 31) << 2;
            int t = li / 3, pos = li - 3*t;
            ushort4 hb = *(const ushort4*)&sH[li*RSH + c4];
            f32x4 v;
            v[0] = bf2f(hb.x); v[1] = bf2f(hb.y); v[2] = bf2f(hb.z); v[3] = bf2f(hb.w);
            *(f32x4*)(go_ + (t*4 + pos)*FDIM + c4) = v;
        }
    }

    __builtin_amdgcn_sched_barrier(0);         // F4

    // ---- P2: pIOU += Uiou @ concat(h_children); C re-inited from AGPR parks ----
    f32x4 pI[2], pU[2], pO[2];
    #pragma unroll
    for (int pt = 0; pt < 2; ++pt)
        #pragma unroll
        for (int r = 0; r < 4; ++r){
            AREADF(pI[pt][r], pIp[pt][r]);
            AREADF(pU[pt][r], pUp[pt][r]);
            AREADF(pO[pt][r], pOp[pt][r]);
        }
    {
        bf16x8 Up[2][3];
        #pragma unroll
        for (int p = 0; p < 2; ++p)
            #pragma unroll
            for (int g = 0; g < 3; ++g)
                Up[p][g] = *(const bf16x8*)(Uiou + (size_t)(g*FDIM + jj)*384 + p*32 + l4*8);
        #pragma unroll
        for (int ks = 0; ks < 12; ++ks){
            bf16x8 A0 = *(const bf16x8*)&sH[(3*l15        + (ks>>2))*RSH + (ks&3)*32 + l4*8];
            bf16x8 A1 = *(const bf16x8*)&sH[(3*(16 + l15) + (ks>>2))*RSH + (ks&3)*32 + l4*8];
            bf16x8 b0 = Up[ks&1][0], b1 = Up[ks&1][1], b2 = Up[ks&1][2];
            if (ks < 10){
                #pragma unroll
                for (int g = 0; g < 3; ++g)
                    Up[ks&1][g] = *(const bf16x8*)(Uiou + (size_t)(g*FDIM + jj)*384 + (ks+2)*32 + l4*8);
            }
            pI[0] = __builtin_amdgcn_mfma_f32_16x16x32_bf16(A0, b0, pI[0], 0,0,0);
            pI[1] = __builtin_amdgcn_mfma_f32_16x16x32_bf16(A1, b0, pI[1], 0,0,0);
            pO[0] = __builtin_amdgcn_mfma_f32_16x16x32_bf16(A0, b1, pO[0], 0,0,0);
            pO[1] = __builtin_amdgcn_mfma_f32_16x16x32_bf16(A1, b1, pO[1], 0,0,0);
            pU[0] = __builtin_amdgcn_mfma_f32_16x16x32_bf16(A0, b2, pU[0], 0,0,0);
            pU[1] = __builtin_amdgcn_mfma_f32_16x16x32_bf16(A1, b2, pU[1], 0,0,0);
        }
    }

    // ---- fold parent gates; park in AGPR ----
    float giup[2][4], gop[2][4];
    #pragma unroll
    for (int pt = 0; pt < 2; ++pt)
        #pragma unroll
        for (int r = 0; r < 4; ++r){
            float giu = sigf(pI[pt][r]+bi) * tanh_(pU[pt][r]+bu);
            float go  = sigf(pO[pt][r]+bo);
            APARKF(giup[pt][r], giu);
            APARKF(gop[pt][r],  go);
        }
    __builtin_amdgcn_sched_barrier(0);         // F5

    // ---- P3: f = sig(FPRE + Uf@h_child); fc = f * cv -> sFC bf16 ----
    {
        bf16x8 Bu[4];
        #pragma unroll
        for (int ks = 0; ks < 4; ++ks)
            Bu[ks] = *(const bf16x8*)(Uf + (size_t)jj*FDIM + ks*32 + l4*8);
        #pragma unroll
        for (int mt = 0; mt < 6; ++mt){
            f32x4 acc = {0.f,0.f,0.f,0.f};
            #pragma unroll
            for (int ks = 0; ks < 4; ++ks){
                bf16x8 A = *(const bf16x8*)&sH[(mt*16 + l15)*RSH + ks*32 + l4*8];
                acc = __builtin_amdgcn_mfma_f32_16x16x32_bf16(A, Bu[ks], acc, 0,0,0);
            }
            #pragma unroll
            for (int rp = 0; rp < 2; ++rp){
                unsigned pk; AREADF(pk, cpk[mt][rp]);
                #pragma unroll
                for (int q = 0; q < 2; ++q){
                    int r = rp*2 + q;
                    int li = mt*16 + l4*4 + r;
                    int t = li / 3, el = li - 3*t;
                    float f  = sigf(acc[r] + bf2f(sAux[t*RS + jj]));
                    float cv = bf2f((unsigned short)((pk >> (16*q)) & 0xffffu));
                    sFC[t*FCRS + el*FDIM + jj] = f2bf(f * cv);
                }
            }
        }
    }
    __syncthreads();                           // B3: sFC complete

    // ---- P4: c_p = i*u + Wc@fc + b_c ; h_p (bf16) -> sAux ----
    {
        const float bc = b_c[jj];
        f32x4 aC0 = {0.f,0.f,0.f,0.f}, aC1 = {0.f,0.f,0.f,0.f};
        #pragma unroll
        for (int ks = 0; ks < 6; ++ks){
            bf16x8 B  = *(const bf16x8*)(Wc + (size_t)jj*384 + ks*32 + l4*8);
            bf16x8 A0 = *(const bf16x8*)&sFC[(l15     )*FCRS + ks*32 + l4*8];
            bf16x8 A1 = *(const bf16x8*)&sFC[(16 + l15)*FCRS + ks*32 + l4*8];
            aC0 = __builtin_amdgcn_mfma_f32_16x16x32_bf16(A0, B, aC0, 0,0,0);
            aC1 = __builtin_amdgcn_mfma_f32_16x16x32_bf16(A1, B, aC1, 0,0,0);
        }
        __builtin_amdgcn_sched_barrier(0);     // F6: split Wc load clusters
        #pragma unroll
        for (int ks = 6; ks < 12; ++ks){
            bf16x8 B  = *(const bf16x8*)(Wc + (size_t)jj*384 + ks*32 + l4*8);
            bf16x8 A0 = *(const bf16x8*)&sFC[(l15     )*FCRS + ks*32 + l4*8];
            bf16x8 A1 = *(const bf16x8*)&sFC[(16 + l15)*FCRS + ks*32 + l4*8];
            aC0 = __builtin_amdgcn_mfma_f32_16x16x32_bf16(A0, B, aC0, 0,0,0);
            aC1 = __builtin_amdgcn_mfma_f32_16x16x32_bf16(A1, B, aC1, 0,0,0);
        }
        #pragma unroll
        for (int pt = 0; pt < 2; ++pt){
            #pragma unroll
            for (int r = 0; r < 4; ++r){
                float giu, go;
                AREADF(giu, giup[pt][r]);
                AREADF(go,  gop[pt][r]);
                float aC = (pt ? aC1 : aC0)[r];
                float cp = giu + aC + bc;
                float hp = go * tanh_(cp);
                sAux[(pt*16 + l4*4 + r)*RS + jj] = f2bf(hp);
            }
        }
    }
    __syncthreads();                           // B4: parent h complete

    // ---- tail dump: 32 parent rows only ----
    {
        float* go_ = Hout + baseN * FDIM;
        #pragma unroll
        for (int it = 0; it < 2; ++it){
            int idx = tid + it * 512;           // 0..1023 float4s
            int t   = idx >> 5;                 // tree 0..31
            int c4  = (idx & 31) << 2;
            ushort4 hb = *(const ushort4*)&sAux[t*RS + c4];
            f32x4 v;
            v[0] = bf2f(hb.x); v[1] = bf2f(hb.y); v[2] = bf2f(hb.z); v[3] = bf2f(hb.w);
            *(f32x4*)(go_ + (t*4 + 3)*FDIM + c4) = v;
        }
    }
}

extern "C" void kernel_launch(void* const* d_in, const int* in_sizes, int n_in,
                              void* d_out, int out_size, void* d_ws, size_t ws_size,
                              hipStream_t stream)
{
    const float* forest = (const float*)d_in[0];
    const float* W_iou  = (const float*)d_in[4];
    const float* b_iou  = (const float*)d_in[5];
    const float* U_iou  = (const float*)d_in[6];
    const float* W_c    = (const float*)d_in[7];
    const float* b_c    = (const float*)d_in[8];
    const float* W_f    = (const float*)d_in[9];
    const float* b_f    = (const float*)d_in[10];
    const float* U_f    = (const float*)d_in[11];
    float* Hout = (float*)d_out;

    unsigned short* wsb = (unsigned short*)d_ws;
    unsigned short* bWiou = wsb;                // 49152 elems
    unsigned short* bUiou = wsb + 49152;        // 147456
    unsigned short* bWc   = wsb + 196608;       // 49152
    unsigned short* bWf   = wsb + 245760;       // 16384
    unsigned short* bUf   = wsb + 262144;       // 16384

    hipLaunchKernelGGL(cvt_all, dim3(272), dim3(256), 0, stream,
                       W_iou, U_iou, W_c, W_f, U_f, wsb);

    const int trees = in_sizes[0] / (4 * FDIM); // 65536
    const int grid  = trees / NTT;              // 2048

    hipLaunchKernelGGL(treelstm_mfma, dim3(grid), dim3(512), 0, stream,
                       forest, bWiou, bUiou, bWc, bWf, bUf, b_iou, b_c, b_f, Hout);
}

// Round 19
// 187.680 us; speedup vs baseline: 1.6465x; 1.0848x over previous
//
#include <hip/hip_runtime.h>

#define FDIM  128
#define NTT   32          // trees per block
#define RS    136         // bf16 row stride for sXb/sAux
#define RSH   144         // bf16 row stride for sH  (288B, 16B-aligned)
#define FCRS  400         // bf16 row stride for sFC (800B, 16B-aligned)

typedef __attribute__((ext_vector_type(8))) short bf16x8;
typedef __attribute__((ext_vector_type(4))) float f32x4;

// explicit AGPR parking (gfx950 unified RF)
#define APARKF(dst, src) asm volatile("v_accvgpr_write_b32 %0, %1" : "=a"(dst) : "v"(src))
#define AREADF(dst, src) asm volatile("v_accvgpr_read_b32 %0, %1"  : "=v"(dst) : "a"(src))

__device__ __forceinline__ unsigned short f2bf(float f){
    unsigned u = __builtin_bit_cast(unsigned, f);
    u += 0x7fffu + ((u >> 16) & 1u);          // RNE
    return (unsigned short)(u >> 16);
}
__device__ __forceinline__ float bf2f(unsigned short b){
    unsigned u = ((unsigned)b) << 16;
    return __builtin_bit_cast(float, u);
}
__device__ __forceinline__ unsigned cvtpk(float lo, float hi){
    unsigned r;
    asm("v_cvt_pk_bf16_f32 %0, %1, %2" : "=v"(r) : "v"(lo), "v"(hi));
    return r;
}
__device__ __forceinline__ float sigf(float x){ return 1.0f/(1.0f+__expf(-x)); }
__device__ __forceinline__ float tanh_(float x){ return 1.0f - 2.0f/(__expf(2.0f*x)+1.0f); }

// ---- fused fp32 -> bf16 conversion of all 5 weight matrices (1 launch) ----
__global__ void cvt_all(const float* __restrict__ W_iou, const float* __restrict__ U_iou,
                        const float* __restrict__ W_c,   const float* __restrict__ W_f,
                        const float* __restrict__ U_f,   unsigned short* __restrict__ dst)
{
    int i = blockIdx.x * 256 + threadIdx.x;      // float4 index, 0..69631
    const float* src; int base;
    if      (i < 12288){ src = W_iou; base = 0; }
    else if (i < 49152){ src = U_iou; base = 12288; }
    else if (i < 61440){ src = W_c;   base = 49152; }
    else if (i < 65536){ src = W_f;   base = 61440; }
    else               { src = U_f;   base = 65536; }
    float4 v = ((const float4*)src)[i - base];
    ushort4 b;
    b.x = f2bf(v.x); b.y = f2bf(v.y); b.z = f2bf(v.z); b.w = f2bf(v.w);
    ((ushort4*)dst)[i] = b;
}

__global__ __launch_bounds__(512, 4) void treelstm_mfma(
    const float* __restrict__ X,
    const unsigned short* __restrict__ Wiou,   // [384][128] bf16
    const unsigned short* __restrict__ Uiou,   // [384][384] bf16
    const unsigned short* __restrict__ Wc,     // [128][384] bf16
    const unsigned short* __restrict__ Wf,     // [128][128] bf16
    const unsigned short* __restrict__ Uf,     // [128][128] bf16
    const float* __restrict__ b_iou,
    const float* __restrict__ b_c,
    const float* __restrict__ b_f,
    float* __restrict__ Hout)
{
    // LDS 62464 B -> 2 blocks/CU
    __shared__ char lds[62464];
    unsigned short* sXb  = (unsigned short*)lds;            // [128][136]; leaves 0..95 (3t+pos), parents 96+t
    unsigned short* sFC  = (unsigned short*)lds;            // [32][400] (alias; leaf-X dead after Pass B)
    unsigned short* sAux = (unsigned short*)(lds + 26112);  // [32][136] FPRE, then parent h
    unsigned short* sH   = (unsigned short*)(lds + 34816);  // [96][144] leaf h

    const int tid  = threadIdx.x;
    const int w    = tid >> 6;
    const int lane = tid & 63;
    const int l15  = lane & 15;
    const int l4   = lane >> 4;
    const int jj   = w * 16 + l15;             // wave's output column (0..127 per gate)
    const size_t baseN = (size_t)blockIdx.x * (NTT*4);

    // ---- P0: load X (128 rows), permute rows, convert bf16 (2x4-load halves) ----
    {
        const f32x4* gx = (const f32x4*)(X + baseN * FDIM);
        #pragma unroll
        for (int it = 0; it < 4; ++it){
            int idx  = tid + it * 512;
            int nrow = idx >> 5;
            int c4   = (idx & 31) << 2;
            int t = nrow >> 2, pos = nrow & 3;
            int srow = (pos < 3) ? (t*3 + pos) : (96 + t);
            f32x4 v = gx[idx];
            uint2 pr; pr.x = cvtpk(v[0], v[1]); pr.y = cvtpk(v[2], v[3]);
            *(uint2*)&sXb[srow * RS + c4] = pr;
        }
        __builtin_amdgcn_sched_barrier(0);     // bound in-flight loads to 4/thread
        #pragma unroll
        for (int it = 4; it < 8; ++it){
            int idx  = tid + it * 512;
            int nrow = idx >> 5;
            int c4   = (idx & 31) << 2;
            int t = nrow >> 2, pos = nrow & 3;
            int srow = (pos < 3) ? (t*3 + pos) : (96 + t);
            f32x4 v = gx[idx];
            uint2 pr; pr.x = cvtpk(v[0], v[1]); pr.y = cvtpk(v[2], v[3]);
            *(uint2*)&sXb[srow * RS + c4] = pr;
        }
    }
    __builtin_amdgcn_sched_barrier(0);

    // ---- Pass-A weights: gates I and U (32 VGPRs); latency hides under barrier ----
    bf16x8 BwI[4], BwU[4];
    #pragma unroll
    for (int ks = 0; ks < 4; ++ks){
        BwI[ks] = *(const bf16x8*)(Wiou + (size_t)(0*FDIM + jj)*FDIM + ks*32 + l4*8);
        BwU[ks] = *(const bf16x8*)(Wiou + (size_t)(2*FDIM + jj)*FDIM + ks*32 + l4*8);
    }
    const float bi = b_iou[jj], bu = b_iou[2*FDIM + jj];
    __syncthreads();                           // B1

    // ---- Pass A: leaf cv = sig(i)*tanh(u) -> packed bf16 AGPR; parents -> pIp,pUp ----
    unsigned cpk[6][2];                        // AGPR-parked cv pairs
    float pIp[2][4], pUp[2][4];                // AGPR-parked parent preacts
    #pragma unroll
    for (int mt = 0; mt < 6; ++mt){
        f32x4 aI = {0.f,0.f,0.f,0.f}, aU = {0.f,0.f,0.f,0.f};
        #pragma unroll
        for (int ks = 0; ks < 4; ++ks){
            bf16x8 A = *(const bf16x8*)&sXb[(mt*16 + l15)*RS + ks*32 + l4*8];
            aI = __builtin_amdgcn_mfma_f32_16x16x32_bf16(A, BwI[ks], aI, 0,0,0);
            aU = __builtin_amdgcn_mfma_f32_16x16x32_bf16(A, BwU[ks], aU, 0,0,0);
        }
        #pragma unroll
        for (int rp = 0; rp < 2; ++rp){
            float cv0 = sigf(aI[rp*2]   + bi) * tanh_(aU[rp*2]   + bu);
            float cv1 = sigf(aI[rp*2+1] + bi) * tanh_(aU[rp*2+1] + bu);
            unsigned pk = cvtpk(cv0, cv1);     // lo16 = cv0, hi16 = cv1
            APARKF(cpk[mt][rp], pk);
        }
    }
    #pragma unroll
    for (int pt = 0; pt < 2; ++pt){
        f32x4 cI = {0.f,0.f,0.f,0.f}, cU = {0.f,0.f,0.f,0.f};
        #pragma unroll
        for (int ks = 0; ks < 4; ++ks){
            bf16x8 A = *(const bf16x8*)&sXb[(96 + pt*16 + l15)*RS + ks*32 + l4*8];
            cI = __builtin_amdgcn_mfma_f32_16x16x32_bf16(A, BwI[ks], cI, 0,0,0);
            cU = __builtin_amdgcn_mfma_f32_16x16x32_bf16(A, BwU[ks], cU, 0,0,0);
        }
        #pragma unroll
        for (int r = 0; r < 4; ++r){ APARKF(pIp[pt][r], cI[r]); APARKF(pUp[pt][r], cU[r]); }
    }
    __builtin_amdgcn_sched_barrier(0);         // F1: keep Pass-B weight loads out of Pass A

    // ---- Pass-B weights: gate O + Wf (reuse freed regs) ----
    bf16x8 BwO[4], Bfr[4];
    #pragma unroll
    for (int ks = 0; ks < 4; ++ks){
        BwO[ks] = *(const bf16x8*)(Wiou + (size_t)(1*FDIM + jj)*FDIM + ks*32 + l4*8);
        Bfr[ks] = *(const bf16x8*)(Wf   + (size_t)jj*FDIM + ks*32 + l4*8);
    }
    const float bo = b_iou[FDIM + jj];

    // ---- Pass B: leaf hv -> sH; parents -> pOp (park), fp (keep in regs) ----
    float pOp[2][4];
    #pragma unroll
    for (int mt = 0; mt < 6; ++mt){
        f32x4 aO = {0.f,0.f,0.f,0.f};
        #pragma unroll
        for (int ks = 0; ks < 4; ++ks){
            bf16x8 A = *(const bf16x8*)&sXb[(mt*16 + l15)*RS + ks*32 + l4*8];
            aO = __builtin_amdgcn_mfma_f32_16x16x32_bf16(A, BwO[ks], aO, 0,0,0);
        }
        #pragma unroll
        for (int rp = 0; rp < 2; ++rp){
            unsigned pk; AREADF(pk, cpk[mt][rp]);
            #pragma unroll
            for (int q = 0; q < 2; ++q){
                int r = rp*2 + q;
                int li = mt*16 + l4*4 + r;     // leaf 0..95
                float cv = bf2f((unsigned short)((pk >> (16*q)) & 0xffffu));
                float hv = sigf(aO[r]+bo) * tanh_(cv);
                sH[li*RSH + jj] = f2bf(hv);
            }
        }
    }
    f32x4 fp[2];
    #pragma unroll
    for (int pt = 0; pt < 2; ++pt){
        f32x4 cO = {0.f,0.f,0.f,0.f};
        fp[pt] = (f32x4){0.f,0.f,0.f,0.f};
        #pragma unroll
        for (int ks = 0; ks < 4; ++ks){
            bf16x8 A = *(const bf16x8*)&sXb[(96 + pt*16 + l15)*RS + ks*32 + l4*8];
            cO     = __builtin_amdgcn_mfma_f32_16x16x32_bf16(A, BwO[ks], cO, 0,0,0);
            fp[pt] = __builtin_amdgcn_mfma_f32_16x16x32_bf16(A, Bfr[ks], fp[pt], 0,0,0);
        }
        #pragma unroll
        for (int r = 0; r < 4; ++r) APARKF(pOp[pt][r], cO[r]);
    }
    __syncthreads();                           // B1.5: all X reads done; sH visible

    // ---- FPRE (bf16) -> sAux (overwrites dead parent-X rows) ----
    const float bfv = b_f[jj];
    #pragma unroll
    for (int pt = 0; pt < 2; ++pt)
        #pragma unroll
        for (int r = 0; r < 4; ++r)
            sAux[(pt*16 + l4*4 + r)*RS + jj] = f2bf(fp[pt][r] + bfv);

    // ---- EARLY leaf-h dump: 96 rows x 512B full lines; overlaps P2/P3/P4 ----
    {
        float* go_ = Hout + baseN * FDIM;
        #pragma unroll
        for (int it = 0; it < 6; ++it){
            int idx  = tid + it * 512;          // 0..3071 float4s
            int li   = idx >> 5;                // leaf 0..95
            int c4   = (idx & 31) << 2;
            int t = li / 3, pos = li - 3*t;
            ushort4 hb = *(const ushort4*)&sH[li*RSH + c4];
            f32x4 v;
            v[0] = bf2f(hb.x); v[1] = bf2f(hb.y); v[2] = bf2f(hb.z); v[3] = bf2f(hb.w);
            *(f32x4*)(go_ + (t*4 + pos)*FDIM + c4) = v;
        }
    }
    // (no fence: let the scheduler overlap dump stores with P2's loads/MFMAs)

    // ---- P2: pIOU += Uiou @ concat(h_children); C re-inited from AGPR parks ----
    f32x4 pI[2], pU[2], pO[2];
    #pragma unroll
    for (int pt = 0; pt < 2; ++pt)
        #pragma unroll
        for (int r = 0; r < 4; ++r){
            AREADF(pI[pt][r], pIp[pt][r]);
            AREADF(pU[pt][r], pUp[pt][r]);
            AREADF(pO[pt][r], pOp[pt][r]);
        }
    {
        bf16x8 Up[2][3];
        #pragma unroll
        for (int p = 0; p < 2; ++p)
            #pragma unroll
            for (int g = 0; g < 3; ++g)
                Up[p][g] = *(const bf16x8*)(Uiou + (size_t)(g*FDIM + jj)*384 + p*32 + l4*8);
        #pragma unroll
        for (int ks = 0; ks < 12; ++ks){
            bf16x8 A0 = *(const bf16x8*)&sH[(3*l15        + (ks>>2))*RSH + (ks&3)*32 + l4*8];
            bf16x8 A1 = *(const bf16x8*)&sH[(3*(16 + l15) + (ks>>2))*RSH + (ks&3)*32 + l4*8];
            bf16x8 b0 = Up[ks&1][0], b1 = Up[ks&1][1], b2 = Up[ks&1][2];
            if (ks < 10){
                #pragma unroll
                for (int g = 0; g < 3; ++g)
                    Up[ks&1][g] = *(const bf16x8*)(Uiou + (size_t)(g*FDIM + jj)*384 + (ks+2)*32 + l4*8);
            }
            pI[0] = __builtin_amdgcn_mfma_f32_16x16x32_bf16(A0, b0, pI[0], 0,0,0);
            pI[1] = __builtin_amdgcn_mfma_f32_16x16x32_bf16(A1, b0, pI[1], 0,0,0);
            pO[0] = __builtin_amdgcn_mfma_f32_16x16x32_bf16(A0, b1, pO[0], 0,0,0);
            pO[1] = __builtin_amdgcn_mfma_f32_16x16x32_bf16(A1, b1, pO[1], 0,0,0);
            pU[0] = __builtin_amdgcn_mfma_f32_16x16x32_bf16(A0, b2, pU[0], 0,0,0);
            pU[1] = __builtin_amdgcn_mfma_f32_16x16x32_bf16(A1, b2, pU[1], 0,0,0);
        }
    }

    // ---- fold parent gates; park in AGPR ----
    float giup[2][4], gop[2][4];
    #pragma unroll
    for (int pt = 0; pt < 2; ++pt)
        #pragma unroll
        for (int r = 0; r < 4; ++r){
            float giu = sigf(pI[pt][r]+bi) * tanh_(pU[pt][r]+bu);
            float go  = sigf(pO[pt][r]+bo);
            APARKF(giup[pt][r], giu);
            APARKF(gop[pt][r],  go);
        }
    // (no fence: let Bu loads hoist under P2 if profitable)

    // ---- P3: f = sig(FPRE + Uf@h_child); fc = f * cv -> sFC bf16 ----
    {
        bf16x8 Bu[4];
        #pragma unroll
        for (int ks = 0; ks < 4; ++ks)
            Bu[ks] = *(const bf16x8*)(Uf + (size_t)jj*FDIM + ks*32 + l4*8);
        #pragma unroll
        for (int mt = 0; mt < 6; ++mt){
            f32x4 acc = {0.f,0.f,0.f,0.f};
            #pragma unroll
            for (int ks = 0; ks < 4; ++ks){
                bf16x8 A = *(const bf16x8*)&sH[(mt*16 + l15)*RSH + ks*32 + l4*8];
                acc = __builtin_amdgcn_mfma_f32_16x16x32_bf16(A, Bu[ks], acc, 0,0,0);
            }
            #pragma unroll
            for (int rp = 0; rp < 2; ++rp){
                unsigned pk; AREADF(pk, cpk[mt][rp]);
                #pragma unroll
                for (int q = 0; q < 2; ++q){
                    int r = rp*2 + q;
                    int li = mt*16 + l4*4 + r;
                    int t = li / 3, el = li - 3*t;
                    float f  = sigf(acc[r] + bf2f(sAux[t*RS + jj]));
                    float cv = bf2f((unsigned short)((pk >> (16*q)) & 0xffffu));
                    sFC[t*FCRS + el*FDIM + jj] = f2bf(f * cv);
                }
            }
        }
    }
    __syncthreads();                           // B3: sFC complete

    // ---- P4: c_p = i*u + Wc@fc + b_c ; h_p (bf16) -> sAux ----
    {
        const float bc = b_c[jj];
        f32x4 aC0 = {0.f,0.f,0.f,0.f}, aC1 = {0.f,0.f,0.f,0.f};
        #pragma unroll
        for (int ks = 0; ks < 12; ++ks){
            bf16x8 B  = *(const bf16x8*)(Wc + (size_t)jj*384 + ks*32 + l4*8);
            bf16x8 A0 = *(const bf16x8*)&sFC[(l15     )*FCRS + ks*32 + l4*8];
            bf16x8 A1 = *(const bf16x8*)&sFC[(16 + l15)*FCRS + ks*32 + l4*8];
            aC0 = __builtin_amdgcn_mfma_f32_16x16x32_bf16(A0, B, aC0, 0,0,0);
            aC1 = __builtin_amdgcn_mfma_f32_16x16x32_bf16(A1, B, aC1, 0,0,0);
        }
        #pragma unroll
        for (int pt = 0; pt < 2; ++pt){
            #pragma unroll
            for (int r = 0; r < 4; ++r){
                float giu, go;
                AREADF(giu, giup[pt][r]);
                AREADF(go,  gop[pt][r]);
                float aC = (pt ? aC1 : aC0)[r];
                float cp = giu + aC + bc;
                float hp = go * tanh_(cp);
                sAux[(pt*16 + l4*4 + r)*RS + jj] = f2bf(hp);
            }
        }
    }
    __syncthreads();                           // B4: parent h complete

    // ---- tail dump: 32 parent rows only ----
    {
        float* go_ = Hout + baseN * FDIM;
        #pragma unroll
        for (int it = 0; it < 2; ++it){
            int idx = tid + it * 512;           // 0..1023 float4s
            int t   = idx >> 5;                 // tree 0..31
            int c4  = (idx & 31) << 2;
            ushort4 hb = *(const ushort4*)&sAux[t*RS + c4];
            f32x4 v;
            v[0] = bf2f(hb.x); v[1] = bf2f(hb.y); v[2] = bf2f(hb.z); v[3] = bf2f(hb.w);
            *(f32x4*)(go_ + (t*4 + 3)*FDIM + c4) = v;
        }
    }
}

extern "C" void kernel_launch(void* const* d_in, const int* in_sizes, int n_in,
                              void* d_out, int out_size, void* d_ws, size_t ws_size,
                              hipStream_t stream)
{
    const float* forest = (const float*)d_in[0];
    const float* W_iou  = (const float*)d_in[4];
    const float* b_iou  = (const float*)d_in[5];
    const float* U_iou  = (const float*)d_in[6];
    const float* W_c    = (const float*)d_in[7];
    const float* b_c    = (const float*)d_in[8];
    const float* W_f    = (const float*)d_in[9];
    const float* b_f    = (const float*)d_in[10];
    const float* U_f    = (const float*)d_in[11];
    float* Hout = (float*)d_out;

    unsigned short* wsb = (unsigned short*)d_ws;
    unsigned short* bWiou = wsb;                // 49152 elems
    unsigned short* bUiou = wsb + 49152;        // 147456
    unsigned short* bWc   = wsb + 196608;       // 49152
    unsigned short* bWf   = wsb + 245760;       // 16384
    unsigned short* bUf   = wsb + 262144;       // 16384

    hipLaunchKernelGGL(cvt_all, dim3(272), dim3(256), 0, stream,
                       W_iou, U_iou, W_c, W_f, U_f, wsb);

    const int trees = in_sizes[0] / (4 * FDIM); // 65536
    const int grid  = trees / NTT;              // 2048

    hipLaunchKernelGGL(treelstm_mfma, dim3(grid), dim3(512), 0, stream,
                       forest, bWiou, bUiou, bWc, bWf, bUf, b_iou, b_c, b_f, Hout);
}

// Round 20
// 184.395 us; speedup vs baseline: 1.6758x; 1.0178x over previous
//
#include <hip/hip_runtime.h>

#define FDIM  128
#define NTT   32          // trees per block
#define RS    136         // bf16 row stride for sXb/sAux
#define RSH   144         // bf16 row stride for sH  (288B, 16B-aligned)
#define FCRS  400         // bf16 row stride for sFC (800B, 16B-aligned)

typedef __attribute__((ext_vector_type(8))) short bf16x8;
typedef __attribute__((ext_vector_type(4))) float f32x4;

// explicit AGPR parking (gfx950 unified RF)
#define APARKF(dst, src) asm volatile("v_accvgpr_write_b32 %0, %1" : "=a"(dst) : "v"(src))
#define AREADF(dst, src) asm volatile("v_accvgpr_read_b32 %0, %1"  : "=v"(dst) : "a"(src))

__device__ __forceinline__ unsigned short f2bf(float f){
    unsigned u = __builtin_bit_cast(unsigned, f);
    u += 0x7fffu + ((u >> 16) & 1u);          // RNE
    return (unsigned short)(u >> 16);
}
__device__ __forceinline__ float bf2f(unsigned short b){
    unsigned u = ((unsigned)b) << 16;
    return __builtin_bit_cast(float, u);
}
__device__ __forceinline__ unsigned cvtpk(float lo, float hi){
    unsigned r;
    asm("v_cvt_pk_bf16_f32 %0, %1, %2" : "=v"(r) : "v"(lo), "v"(hi));
    return r;
}
__device__ __forceinline__ float sigf(float x){ return 1.0f/(1.0f+__expf(-x)); }
__device__ __forceinline__ float tanh_(float x){ return 1.0f - 2.0f/(__expf(2.0f*x)+1.0f); }

// ---- fused fp32 -> bf16 conversion of all 5 weight matrices (1 launch) ----
__global__ void cvt_all(const float* __restrict__ W_iou, const float* __restrict__ U_iou,
                        const float* __restrict__ W_c,   const float* __restrict__ W_f,
                        const float* __restrict__ U_f,   unsigned short* __restrict__ dst)
{
    int i = blockIdx.x * 256 + threadIdx.x;      // float4 index, 0..69631
    const float* src; int base;
    if      (i < 12288){ src = W_iou; base = 0; }
    else if (i < 49152){ src = U_iou; base = 12288; }
    else if (i < 61440){ src = W_c;   base = 49152; }
    else if (i < 65536){ src = W_f;   base = 61440; }
    else               { src = U_f;   base = 65536; }
    float4 v = ((const float4*)src)[i - base];
    ushort4 b;
    b.x = f2bf(v.x); b.y = f2bf(v.y); b.z = f2bf(v.z); b.w = f2bf(v.w);
    ((ushort4*)dst)[i] = b;
}

__global__ __launch_bounds__(512, 4) void treelstm_mfma(
    const float* __restrict__ X,
    const unsigned short* __restrict__ Wiou,   // [384][128] bf16
    const unsigned short* __restrict__ Uiou,   // [384][384] bf16
    const unsigned short* __restrict__ Wc,     // [128][384] bf16
    const unsigned short* __restrict__ Wf,     // [128][128] bf16
    const unsigned short* __restrict__ Uf,     // [128][128] bf16
    const float* __restrict__ b_iou,
    const float* __restrict__ b_c,
    const float* __restrict__ b_f,
    float* __restrict__ Hout)
{
    // LDS 62464 B -> 2 blocks/CU
    __shared__ char lds[62464];
    unsigned short* sXb  = (unsigned short*)lds;            // [128][136]; leaves 0..95 (3t+pos), parents 96+t
    unsigned short* sFC  = (unsigned short*)lds;            // [32][400] (alias; leaf-X dead after Pass B)
    unsigned short* sAux = (unsigned short*)(lds + 26112);  // [32][136] FPRE, then parent h
    unsigned short* sH   = (unsigned short*)(lds + 34816);  // [96][144] leaf h

    const int tid  = threadIdx.x;
    const int w    = tid >> 6;
    const int lane = tid & 63;
    const int l15  = lane & 15;
    const int l4   = lane >> 4;
    const int jj   = w * 16 + l15;             // wave's output column (0..127 per gate)
    const size_t baseN = (size_t)blockIdx.x * (NTT*4);

    // ---- P0: load X (128 rows), permute rows, convert bf16 (unbounded ILP) ----
    {
        const f32x4* gx = (const f32x4*)(X + baseN * FDIM);
        #pragma unroll
        for (int it = 0; it < 8; ++it){
            int idx  = tid + it * 512;
            int nrow = idx >> 5;
            int c4   = (idx & 31) << 2;
            int t = nrow >> 2, pos = nrow & 3;
            int srow = (pos < 3) ? (t*3 + pos) : (96 + t);
            f32x4 v = gx[idx];
            uint2 pr; pr.x = cvtpk(v[0], v[1]); pr.y = cvtpk(v[2], v[3]);
            *(uint2*)&sXb[srow * RS + c4] = pr;
        }
    }

    // ---- Pass-A weights: gates I and U (32 VGPRs); latency hides under barrier ----
    bf16x8 BwI[4], BwU[4];
    #pragma unroll
    for (int ks = 0; ks < 4; ++ks){
        BwI[ks] = *(const bf16x8*)(Wiou + (size_t)(0*FDIM + jj)*FDIM + ks*32 + l4*8);
        BwU[ks] = *(const bf16x8*)(Wiou + (size_t)(2*FDIM + jj)*FDIM + ks*32 + l4*8);
    }
    const float bi = b_iou[jj], bu = b_iou[2*FDIM + jj];
    __syncthreads();                           // B1

    // ---- Pass A: leaf cv = sig(i)*tanh(u) -> packed bf16 AGPR; parents -> pIp,pUp ----
    unsigned cpk[6][2];                        // AGPR-parked cv pairs
    float pIp[2][4], pUp[2][4];                // AGPR-parked parent preacts
    #pragma unroll
    for (int mt = 0; mt < 6; ++mt){
        f32x4 aI = {0.f,0.f,0.f,0.f}, aU = {0.f,0.f,0.f,0.f};
        #pragma unroll
        for (int ks = 0; ks < 4; ++ks){
            bf16x8 A = *(const bf16x8*)&sXb[(mt*16 + l15)*RS + ks*32 + l4*8];
            aI = __builtin_amdgcn_mfma_f32_16x16x32_bf16(A, BwI[ks], aI, 0,0,0);
            aU = __builtin_amdgcn_mfma_f32_16x16x32_bf16(A, BwU[ks], aU, 0,0,0);
        }
        #pragma unroll
        for (int rp = 0; rp < 2; ++rp){
            float cv0 = sigf(aI[rp*2]   + bi) * tanh_(aU[rp*2]   + bu);
            float cv1 = sigf(aI[rp*2+1] + bi) * tanh_(aU[rp*2+1] + bu);
            unsigned pk = cvtpk(cv0, cv1);     // lo16 = cv0, hi16 = cv1
            APARKF(cpk[mt][rp], pk);
        }
    }
    #pragma unroll
    for (int pt = 0; pt < 2; ++pt){
        f32x4 cI = {0.f,0.f,0.f,0.f}, cU = {0.f,0.f,0.f,0.f};
        #pragma unroll
        for (int ks = 0; ks < 4; ++ks){
            bf16x8 A = *(const bf16x8*)&sXb[(96 + pt*16 + l15)*RS + ks*32 + l4*8];
            cI = __builtin_amdgcn_mfma_f32_16x16x32_bf16(A, BwI[ks], cI, 0,0,0);
            cU = __builtin_amdgcn_mfma_f32_16x16x32_bf16(A, BwU[ks], cU, 0,0,0);
        }
        #pragma unroll
        for (int r = 0; r < 4; ++r){ APARKF(pIp[pt][r], cI[r]); APARKF(pUp[pt][r], cU[r]); }
    }
    __builtin_amdgcn_sched_barrier(0);         // F1: keep Pass-B weight loads out of Pass A

    // ---- Pass-B weights: gate O + Wf (reuse freed regs) ----
    bf16x8 BwO[4], Bfr[4];
    #pragma unroll
    for (int ks = 0; ks < 4; ++ks){
        BwO[ks] = *(const bf16x8*)(Wiou + (size_t)(1*FDIM + jj)*FDIM + ks*32 + l4*8);
        Bfr[ks] = *(const bf16x8*)(Wf   + (size_t)jj*FDIM + ks*32 + l4*8);
    }
    const float bo = b_iou[FDIM + jj];

    // ---- Pass B: leaf hv -> sH; parents -> pOp (park), fp (keep in regs) ----
    float pOp[2][4];
    #pragma unroll
    for (int mt = 0; mt < 6; ++mt){
        f32x4 aO = {0.f,0.f,0.f,0.f};
        #pragma unroll
        for (int ks = 0; ks < 4; ++ks){
            bf16x8 A = *(const bf16x8*)&sXb[(mt*16 + l15)*RS + ks*32 + l4*8];
            aO = __builtin_amdgcn_mfma_f32_16x16x32_bf16(A, BwO[ks], aO, 0,0,0);
        }
        #pragma unroll
        for (int rp = 0; rp < 2; ++rp){
            unsigned pk; AREADF(pk, cpk[mt][rp]);
            #pragma unroll
            for (int q = 0; q < 2; ++q){
                int r = rp*2 + q;
                int li = mt*16 + l4*4 + r;     // leaf 0..95
                float cv = bf2f((unsigned short)((pk >> (16*q)) & 0xffffu));
                float hv = sigf(aO[r]+bo) * tanh_(cv);
                sH[li*RSH + jj] = f2bf(hv);
            }
        }
    }
    f32x4 fp[2];
    #pragma unroll
    for (int pt = 0; pt < 2; ++pt){
        f32x4 cO = {0.f,0.f,0.f,0.f};
        fp[pt] = (f32x4){0.f,0.f,0.f,0.f};
        #pragma unroll
        for (int ks = 0; ks < 4; ++ks){
            bf16x8 A = *(const bf16x8*)&sXb[(96 + pt*16 + l15)*RS + ks*32 + l4*8];
            cO     = __builtin_amdgcn_mfma_f32_16x16x32_bf16(A, BwO[ks], cO, 0,0,0);
            fp[pt] = __builtin_amdgcn_mfma_f32_16x16x32_bf16(A, Bfr[ks], fp[pt], 0,0,0);
        }
        #pragma unroll
        for (int r = 0; r < 4; ++r) APARKF(pOp[pt][r], cO[r]);
    }
    __syncthreads();                           // B1.5: all X reads done; sH visible

    // ---- FPRE (bf16) -> sAux (overwrites dead parent-X rows) ----
    const float bfv = b_f[jj];
    #pragma unroll
    for (int pt = 0; pt < 2; ++pt)
        #pragma unroll
        for (int r = 0; r < 4; ++r)
            sAux[(pt*16 + l4*4 + r)*RS + jj] = f2bf(fp[pt][r] + bfv);

    // ---- EARLY leaf-h dump: 96 rows x 512B full lines; overlaps P2/P3/P4 ----
    {
        float* go_ = Hout + baseN * FDIM;
        #pragma unroll
        for (int it = 0; it < 6; ++it){
            int idx  = tid + it * 512;          // 0..3071 float4s
            int li   = idx >> 5;                // leaf 0..95
            int c4   = (idx & 31) << 2;
            int t = li / 3, pos = li - 3*t;
            ushort4 hb = *(const ushort4*)&sH[li*RSH + c4];
            f32x4 v;
            v[0] = bf2f(hb.x); v[1] = bf2f(hb.y); v[2] = bf2f(hb.z); v[3] = bf2f(hb.w);
            *(f32x4*)(go_ + (t*4 + pos)*FDIM + c4) = v;
        }
    }
    // (no fence: scheduler overlaps dump stores with P2's loads/MFMAs)

    // ---- P2: pIOU += Uiou @ concat(h_children); C re-inited from AGPR parks ----
    f32x4 pI[2], pU[2], pO[2];
    #pragma unroll
    for (int pt = 0; pt < 2; ++pt)
        #pragma unroll
        for (int r = 0; r < 4; ++r){
            AREADF(pI[pt][r], pIp[pt][r]);
            AREADF(pU[pt][r], pUp[pt][r]);
            AREADF(pO[pt][r], pOp[pt][r]);
        }
    {
        bf16x8 Up[2][3];
        #pragma unroll
        for (int p = 0; p < 2; ++p)
            #pragma unroll
            for (int g = 0; g < 3; ++g)
                Up[p][g] = *(const bf16x8*)(Uiou + (size_t)(g*FDIM + jj)*384 + p*32 + l4*8);
        #pragma unroll
        for (int ks = 0; ks < 12; ++ks){
            bf16x8 A0 = *(const bf16x8*)&sH[(3*l15        + (ks>>2))*RSH + (ks&3)*32 + l4*8];
            bf16x8 A1 = *(const bf16x8*)&sH[(3*(16 + l15) + (ks>>2))*RSH + (ks&3)*32 + l4*8];
            bf16x8 b0 = Up[ks&1][0], b1 = Up[ks&1][1], b2 = Up[ks&1][2];
            if (ks < 10){
                #pragma unroll
                for (int g = 0; g < 3; ++g)
                    Up[ks&1][g] = *(const bf16x8*)(Uiou + (size_t)(g*FDIM + jj)*384 + (ks+2)*32 + l4*8);
            }
            pI[0] = __builtin_amdgcn_mfma_f32_16x16x32_bf16(A0, b0, pI[0], 0,0,0);
            pI[1] = __builtin_amdgcn_mfma_f32_16x16x32_bf16(A1, b0, pI[1], 0,0,0);
            pO[0] = __builtin_amdgcn_mfma_f32_16x16x32_bf16(A0, b1, pO[0], 0,0,0);
            pO[1] = __builtin_amdgcn_mfma_f32_16x16x32_bf16(A1, b1, pO[1], 0,0,0);
            pU[0] = __builtin_amdgcn_mfma_f32_16x16x32_bf16(A0, b2, pU[0], 0,0,0);
            pU[1] = __builtin_amdgcn_mfma_f32_16x16x32_bf16(A1, b2, pU[1], 0,0,0);
        }
    }

    // ---- fold parent gates; park in AGPR ----
    float giup[2][4], gop[2][4];
    #pragma unroll
    for (int pt = 0; pt < 2; ++pt)
        #pragma unroll
        for (int r = 0; r < 4; ++r){
            float giu = sigf(pI[pt][r]+bi) * tanh_(pU[pt][r]+bu);
            float go  = sigf(pO[pt][r]+bo);
            APARKF(giup[pt][r], giu);
            APARKF(gop[pt][r],  go);
        }

    // ---- P3: f = sig(FPRE + Uf@h_child); fc = f * cv -> sFC bf16 ----
    {
        bf16x8 Bu[4];
        #pragma unroll
        for (int ks = 0; ks < 4; ++ks)
            Bu[ks] = *(const bf16x8*)(Uf + (size_t)jj*FDIM + ks*32 + l4*8);
        #pragma unroll
        for (int mt = 0; mt < 6; ++mt){
            f32x4 acc = {0.f,0.f,0.f,0.f};
            #pragma unroll
            for (int ks = 0; ks < 4; ++ks){
                bf16x8 A = *(const bf16x8*)&sH[(mt*16 + l15)*RSH + ks*32 + l4*8];
                acc = __builtin_amdgcn_mfma_f32_16x16x32_bf16(A, Bu[ks], acc, 0,0,0);
            }
            #pragma unroll
            for (int rp = 0; rp < 2; ++rp){
                unsigned pk; AREADF(pk, cpk[mt][rp]);
                #pragma unroll
                for (int q = 0; q < 2; ++q){
                    int r = rp*2 + q;
                    int li = mt*16 + l4*4 + r;
                    int t = li / 3, el = li - 3*t;
                    float f  = sigf(acc[r] + bf2f(sAux[t*RS + jj]));
                    float cv = bf2f((unsigned short)((pk >> (16*q)) & 0xffffu));
                    sFC[t*FCRS + el*FDIM + jj] = f2bf(f * cv);
                }
            }
        }
    }
    __syncthreads();                           // B3: sFC complete

    // ---- P4: c_p = i*u + Wc@fc + b_c ; h_p (bf16) -> sAux ----
    {
        const float bc = b_c[jj];
        f32x4 aC0 = {0.f,0.f,0.f,0.f}, aC1 = {0.f,0.f,0.f,0.f};
        #pragma unroll
        for (int ks = 0; ks < 12; ++ks){
            bf16x8 B  = *(const bf16x8*)(Wc + (size_t)jj*384 + ks*32 + l4*8);
            bf16x8 A0 = *(const bf16x8*)&sFC[(l15     )*FCRS + ks*32 + l4*8];
            bf16x8 A1 = *(const bf16x8*)&sFC[(16 + l15)*FCRS + ks*32 + l4*8];
            aC0 = __builtin_amdgcn_mfma_f32_16x16x32_bf16(A0, B, aC0, 0,0,0);
            aC1 = __builtin_amdgcn_mfma_f32_16x16x32_bf16(A1, B, aC1, 0,0,0);
        }
        #pragma unroll
        for (int pt = 0; pt < 2; ++pt){
            #pragma unroll
            for (int r = 0; r < 4; ++r){
                float giu, go;
                AREADF(giu, giup[pt][r]);
                AREADF(go,  gop[pt][r]);
                float aC = (pt ? aC1 : aC0)[r];
                float cp = giu + aC + bc;
                float hp = go * tanh_(cp);
                sAux[(pt*16 + l4*4 + r)*RS + jj] = f2bf(hp);
            }
        }
    }
    __syncthreads();                           // B4: parent h complete

    // ---- tail dump: 32 parent rows only ----
    {
        float* go_ = Hout + baseN * FDIM;
        #pragma unroll
        for (int it = 0; it < 2; ++it){
            int idx = tid + it * 512;           // 0..1023 float4s
            int t   = idx >> 5;                 // tree 0..31
            int c4  = (idx & 31) << 2;
            ushort4 hb = *(const ushort4*)&sAux[t*RS + c4];
            f32x4 v;
            v[0] = bf2f(hb.x); v[1] = bf2f(hb.y); v[2] = bf2f(hb.z); v[3] = bf2f(hb.w);
            *(f32x4*)(go_ + (t*4 + 3)*FDIM + c4) = v;
        }
    }
}

extern "C" void kernel_launch(void* const* d_in, const int* in_sizes, int n_in,
                              void* d_out, int out_size, void* d_ws, size_t ws_size,
                              hipStream_t stream)
{
    const float* forest = (const float*)d_in[0];
    const float* W_iou  = (const float*)d_in[4];
    const float* b_iou  = (const float*)d_in[5];
    const float* U_iou  = (const float*)d_in[6];
    const float* W_c    = (const float*)d_in[7];
    const float* b_c    = (const float*)d_in[8];
    const float* W_f    = (const float*)d_in[9];
    const float* b_f    = (const float*)d_in[10];
    const float* U_f    = (const float*)d_in[11];
    float* Hout = (float*)d_out;

    unsigned short* wsb = (unsigned short*)d_ws;
    unsigned short* bWiou = wsb;                // 49152 elems
    unsigned short* bUiou = wsb + 49152;        // 147456
    unsigned short* bWc   = wsb + 196608;       // 49152
    unsigned short* bWf   = wsb + 245760;       // 16384
    unsigned short* bUf   = wsb + 262144;       // 16384

    hipLaunchKernelGGL(cvt_all, dim3(272), dim3(256), 0, stream,
                       W_iou, U_iou, W_c, W_f, U_f, wsb);

    const int trees = in_sizes[0] / (4 * FDIM); // 65536
    const int grid  = trees / NTT;              // 2048

    hipLaunchKernelGGL(treelstm_mfma, dim3(grid), dim3(512), 0, stream,
                       forest, bWiou, bUiou, bWc, bWf, bUf, b_iou, b_c, b_f, Hout);
}